// Round 17
// baseline (2272.986 us; speedup 1.0000x reference)
//
#include <hip/hip_runtime.h>

#define T_SEQ  1024
#define NBATCH 512
#define IN_DIM 16
#define HDIM   128
#define G4     (4 * HDIM)
#define TC     64
#define NCHUNK (T_SEQ / TC)
#define NWGH   128   // merged WGs; 4 batches each (both roles)

typedef unsigned short ushort_t;
typedef __attribute__((ext_vector_type(8))) _Float16 f16x8;
typedef __attribute__((ext_vector_type(4))) float f32x4;

#define MFMA16(a, b, c) __builtin_amdgcn_mfma_f32_16x16x32_f16((a), (b), (c), 0, 0, 0)

__device__ __forceinline__ float sigf(float x) {
  return __builtin_amdgcn_rcpf(1.0f + __expf(-x));
}
__device__ __forceinline__ float tanhf_fast(float x) {
  return 1.0f - 2.0f * __builtin_amdgcn_rcpf(1.0f + __expf(2.0f * x));
}
__device__ __forceinline__ ushort_t f16_bits(float f) {
  const _Float16 h = (_Float16)f;
  return __builtin_bit_cast(unsigned short, h);
}
__device__ __forceinline__ void split_f16(float f, ushort_t* hi, ushort_t* lo) {
  const _Float16 h = (_Float16)f;
  *hi = __builtin_bit_cast(unsigned short, h);
  const _Float16 l = (_Float16)(f - (float)h);
  *lo = __builtin_bit_cast(unsigned short, l);
}
// barrier that waits only on LDS ops (global stores stay in flight)
__device__ __forceinline__ void bar_lds() {
  asm volatile("s_waitcnt lgkmcnt(0)\n\ts_barrier" ::: "memory");
}

// ---------------- prep: split weights into fp16 hi/lo ----------------
__global__ __launch_bounds__(256) void prep_weights(
    const float* __restrict__ Whh0, const float* __restrict__ Whh1,
    const float* __restrict__ Wih0, const float* __restrict__ Wih1,
    ushort_t* __restrict__ w0h, ushort_t* __restrict__ w0l,
    ushort_t* __restrict__ w1h, ushort_t* __restrict__ w1l,
    ushort_t* __restrict__ wxh, ushort_t* __restrict__ wxl,
    ushort_t* __restrict__ wi1h, ushort_t* __restrict__ wi1l)
{
  const int idx = blockIdx.x * 256 + threadIdx.x;
  if (idx < 512 * HDIM) {
    split_f16(Whh0[idx], &w0h[idx], &w0l[idx]);
    split_f16(Whh1[idx], &w1h[idx], &w1l[idx]);
    split_f16(Wih1[idx], &wi1h[idx], &wi1l[idx]);
  }
  if (idx < 512 * 32) {  // Wih0 zero-padded K=16 -> 32
    const int g = idx >> 5, k = idx & 31;
    const float f = (k < IN_DIM) ? Wih0[g * IN_DIM + k] : 0.0f;
    split_f16(f, &wxh[idx], &wxl[idx]);
  }
}

// Per-role LDS pools (both live; 84.2 + 72.4 = 153 KB <= 160 KB/CU)
struct L0LDS {
  __align__(16) ushort_t hfA[4][144];
  __align__(16) ushort_t hfB[4][144];
  __align__(16) ushort_t xlds[4][TC][32];
  __align__(16) float gx0s[8 * 4 * 128 * 4];  // [t_local][b][j][gate]
};
struct L1LDS {
  __align__(16) ushort_t hfA[4][144];
  __align__(16) ushort_t hfB[4][144];
  __align__(16) ushort_t h2l[TC][4][136];
  __align__(16) float wfl[HDIM];
};

// ---------------- merged-role pipelined kernel ----------------
// One 1024-thread WG per 4-batch group (grid 128): threads [0,512) run
// L0(ch), threads [512,1024) run gemm+L1(ch-1). Both halves execute an
// IDENTICAL barrier skeleton: 1 syncthreads + per sub-chunk {work;
// syncthreads; 8 x (step; bar_lds)} = 73 barriers. Inactive halves
// (first/last launch) run a barrier-only skeleton. Cross-launch h1buf
// handoff unchanged. 4 waves/SIMD (2 L0 + 2 L1) hide each other's
// serial chains. Recurrent W terms fp16-hi only (validated R14-R16).
__global__ __launch_bounds__(1024) void lstm_pipe(
    const float* __restrict__ x,
    const ushort_t* __restrict__ w0h,
    const ushort_t* __restrict__ wxh, const ushort_t* __restrict__ wxl,
    const float* __restrict__ bih0, const float* __restrict__ bhh0,
    const ushort_t* __restrict__ wi1h,
    const ushort_t* __restrict__ w1h,
    const float* __restrict__ bih1, const float* __restrict__ bhh1,
    const float* __restrict__ Wfc, const float* __restrict__ bfc,
    float* __restrict__ out,
    float* __restrict__ h1s, float* __restrict__ c1s,
    float* __restrict__ h2s, float* __restrict__ c2s,
    ushort_t* __restrict__ h1buf,   // [2][NWGH][TC*4][HDIM] fp16
    float* __restrict__ gx1buf,     // [NWGH][TC*4][HDIM][4]
    int ch)
{
  const int tid  = threadIdx.x;
  const int ltid = tid & 511;
  const int lane = tid & 63;
  const int wv   = (tid >> 6) & 7;
  const int row  = lane & 15;
  const int kq   = lane >> 4;    // update-phase batch
  const int bq   = row >> 2;     // A-fragment batch for this lane's A row
  const int j    = wv * 16 + row;
  const int w    = blockIdx.x;
  const int b0   = w * 4;

  __shared__ L0LDS S0;
  __shared__ L1LDS S1;

  if (tid < 512) {
    // ================= L0 HALF: chunk ch =================
    if (ch >= NCHUNK) {  // inactive: barrier skeleton only
      __syncthreads();
      for (int sc = 0; sc < TC / 8; ++sc) {
        __syncthreads();
        for (int q = 0; q < 8; ++q) bar_lds();
      }
      return;
    }

    f16x8 Bh[4][4];
#pragma unroll
    for (int i = 0; i < 4; ++i) {
      const int g = i * 128 + j;
#pragma unroll
      for (int kt = 0; kt < 4; ++kt)
        Bh[i][kt] = *(const f16x8*)&w0h[g * HDIM + kt * 32 + kq * 8];
    }

    // stage this chunk's x as fp16 (2 threads per (b,ts) row)
    {
      const int r = ltid >> 1, half = ltid & 1;
      const int b = r >> 6, ts = r & (TC - 1);
      const float* src =
          &x[((size_t)(b0 + b) * T_SEQ + ch * TC + ts) * IN_DIM + half * 8];
      const float4 v0 = *(const float4*)&src[0];
      const float4 v1 = *(const float4*)&src[4];
      ushort_t* dst = &S0.xlds[b][ts][half * 8];
      dst[0] = f16_bits(v0.x); dst[1] = f16_bits(v0.y);
      dst[2] = f16_bits(v0.z); dst[3] = f16_bits(v0.w);
      dst[4] = f16_bits(v1.x); dst[5] = f16_bits(v1.y);
      dst[6] = f16_bits(v1.z); dst[7] = f16_bits(v1.w);
      *(float4*)&S0.xlds[b][ts][16 + half * 8] = (float4){0.f, 0.f, 0.f, 0.f};
    }

    float bz[4];
#pragma unroll
    for (int i = 0; i < 4; ++i) bz[i] = bih0[i * 128 + j] + bhh0[i * 128 + j];
    float hc = h1s[(size_t)(b0 + kq) * HDIM + j];
    float cc = c1s[(size_t)(b0 + kq) * HDIM + j];
    S0.hfA[kq][j] = f16_bits(hc);
    __syncthreads();

    ushort_t* hbp = h1buf + ((size_t)(ch & 1) * NWGH + w) * (TC * 4 * HDIM) +
                    (size_t)kq * HDIM + j;

#define L0_STEP(HIN, HOUT, TT)                                              \
  {                                                                         \
    const float4 zcu =                                                      \
        *(const float4*)&S0.gx0s[((((TT) & 7) * 4 + kq) * 128 + j) * 4];    \
    f32x4 aH[4];                                                            \
    _Pragma("unroll") for (int i = 0; i < 4; ++i)                           \
        aH[i] = (f32x4){0.f, 0.f, 0.f, 0.f};                                \
    _Pragma("unroll") for (int kt = 0; kt < 4; ++kt) {                      \
      const f16x8 ah = *(const f16x8*)&S0.HIN[bq][kt * 32 + kq * 8];        \
      _Pragma("unroll") for (int i = 0; i < 4; ++i)                         \
          aH[i] = MFMA16(ah, Bh[i][kt], aH[i]);                             \
    }                                                                       \
    const float ig = sigf(aH[0][0] + zcu.x);                                \
    const float fg = sigf(aH[1][0] + zcu.y);                                \
    const float gg = tanhf_fast(aH[2][0] + zcu.z);                          \
    const float og = sigf(aH[3][0] + zcu.w);                                \
    cc = fg * cc + ig * gg;                                                 \
    hc = og * tanhf_fast(cc);                                               \
    const ushort_t hbits = f16_bits(hc);                                    \
    S0.HOUT[kq][j] = hbits;                                                 \
    *hbp = hbits;                                                           \
    hbp += 4 * HDIM;                                                        \
    bar_lds();                                                              \
  }

    for (int sc = 0; sc < TC / 8; ++sc) {
      // ---- sub-chunk x-GEMM: gx0 = x . Wih0^T + bias (hi+lo) -> LDS ----
      {
        f16x8 Bxh[4], Bxl[4];
#pragma unroll
        for (int i = 0; i < 4; ++i) {
          const int g = i * 128 + j;
          Bxh[i] = *(const f16x8*)&wxh[g * 32 + kq * 8];
          Bxl[i] = *(const f16x8*)&wxl[g * 32 + kq * 8];
        }
#pragma unroll
        for (int mt = 0; mt < 2; ++mt) {
          const f16x8 a = *(const f16x8*)
              &S0.xlds[row & 3][sc * 8 + mt * 4 + (row >> 2)][kq * 8];
          f32x4 acc[4];
#pragma unroll
          for (int i = 0; i < 4; ++i) acc[i] = (f32x4){0.f, 0.f, 0.f, 0.f};
#pragma unroll
          for (int i = 0; i < 4; ++i) acc[i] = MFMA16(a, Bxh[i], acc[i]);
#pragma unroll
          for (int i = 0; i < 4; ++i) acc[i] = MFMA16(a, Bxl[i], acc[i]);
#pragma unroll
          for (int r = 0; r < 4; ++r) {
            float4 o;
            o.x = acc[0][r] + bz[0];
            o.y = acc[1][r] + bz[1];
            o.z = acc[2][r] + bz[2];
            o.w = acc[3][r] + bz[3];
            *(float4*)&S0.gx0s[(((mt * 4 + kq) * 4 + r) * 128 + j) * 4] = o;
          }
        }
      }
      __syncthreads();
#pragma unroll 1
      for (int q = 0; q < 4; ++q) {
        const int tt = sc * 8 + q * 2;
        L0_STEP(hfA, hfB, tt);
        L0_STEP(hfB, hfA, tt + 1);
      }
    }
#undef L0_STEP

    h1s[(size_t)(b0 + kq) * HDIM + j] = hc;
    c1s[(size_t)(b0 + kq) * HDIM + j] = cc;
  } else {
    // ================= L1 HALF: gemm + recurrence, chunk ch-1 =============
    if (ch == 0) {  // inactive: barrier skeleton only
      __syncthreads();
      for (int sc = 0; sc < TC / 8; ++sc) {
        __syncthreads();
        for (int q = 0; q < 8; ++q) bar_lds();
      }
      return;
    }

    const ushort_t* hb =
        h1buf + ((size_t)((ch - 1) & 1) * NWGH + w) * (TC * 4 * HDIM);
    float* gx = gx1buf + (size_t)w * (TC * 4 * HDIM * 4);

    if (ltid < HDIM) S1.wfl[ltid] = Wfc[ltid];

    float bz1[4];
#pragma unroll
    for (int i = 0; i < 4; ++i) bz1[i] = bih1[i * 128 + j] + bhh1[i * 128 + j];
    f16x8 Rh[4][4];
#pragma unroll
    for (int i = 0; i < 4; ++i) {
      const int g = i * 128 + j;
#pragma unroll
      for (int kt = 0; kt < 4; ++kt)
        Rh[i][kt] = *(const f16x8*)&w1h[g * HDIM + kt * 32 + kq * 8];
    }

    float hc = h2s[(size_t)(b0 + kq) * HDIM + j];
    float cc = c2s[(size_t)(b0 + kq) * HDIM + j];
    S1.hfA[kq][j] = f16_bits(hc);
    __syncthreads();

#define L1_STEP(HIN, HOUT, TT, ZCU)                                         \
  {                                                                         \
    f32x4 aH[4];                                                            \
    _Pragma("unroll") for (int i = 0; i < 4; ++i)                           \
        aH[i] = (f32x4){0.f, 0.f, 0.f, 0.f};                                \
    _Pragma("unroll") for (int kt = 0; kt < 4; ++kt) {                      \
      const f16x8 ah = *(const f16x8*)&S1.HIN[bq][kt * 32 + kq * 8];        \
      _Pragma("unroll") for (int i = 0; i < 4; ++i)                         \
          aH[i] = MFMA16(ah, Rh[i][kt], aH[i]);                             \
    }                                                                       \
    const float ig = sigf(aH[0][0] + (ZCU).x);                              \
    const float fg = sigf(aH[1][0] + (ZCU).y);                              \
    const float gg = tanhf_fast(aH[2][0] + (ZCU).z);                        \
    const float og = sigf(aH[3][0] + (ZCU).w);                              \
    cc = fg * cc + ig * gg;                                                 \
    hc = og * tanhf_fast(cc);                                               \
    const ushort_t hbits = f16_bits(hc);                                    \
    S1.HOUT[kq][j] = hbits;                                                 \
    S1.h2l[TT][kq][j] = hbits;                                              \
    bar_lds();                                                              \
  }

    for (int sc = 0; sc < TC / 8; ++sc) {
      // ---- sub-chunk gx1 GEMM (hi only): rows sc*32..sc*32+31 ----
      {
        f16x8 Gh[4][4];
#pragma unroll
        for (int i = 0; i < 4; ++i) {
          const int g = i * 128 + j;
#pragma unroll
          for (int kt = 0; kt < 4; ++kt)
            Gh[i][kt] = *(const f16x8*)&wi1h[g * HDIM + kt * 32 + kq * 8];
        }
#pragma unroll
        for (int mt2 = 0; mt2 < 2; ++mt2) {
          const int m0 = sc * 32 + mt2 * 16;
          f32x4 acc[4];
#pragma unroll
          for (int i = 0; i < 4; ++i) acc[i] = (f32x4){0.f, 0.f, 0.f, 0.f};
#pragma unroll
          for (int kt = 0; kt < 4; ++kt) {
            const f16x8 a =
                *(const f16x8*)&hb[(size_t)(m0 + row) * HDIM + kt * 32 + kq * 8];
#pragma unroll
            for (int i = 0; i < 4; ++i) acc[i] = MFMA16(a, Gh[i][kt], acc[i]);
          }
#pragma unroll
          for (int r = 0; r < 4; ++r) {
            const int m = m0 + kq * 4 + r;
            float4 o;
            o.x = acc[0][r] + bz1[0];
            o.y = acc[1][r] + bz1[1];
            o.z = acc[2][r] + bz1[2];
            o.w = acc[3][r] + bz1[3];
            *(float4*)&gx[((size_t)m * HDIM + j) * 4] = o;
          }
        }
      }
      __syncthreads();  // vmcnt drain: gx stores visible to step reads

      // step-wise zc with in-sub-chunk prefetch (stride 512 float4/step)
      const float4* gxp =
          (const float4*)gx + ((size_t)(sc * 8 * 4 + kq) * HDIM + j);
      float4 zcc = *gxp;
      gxp += 512;
#pragma unroll 1
      for (int q = 0; q < 4; ++q) {
        const int tt = sc * 8 + q * 2;
        float4 z0 = zcc;
        zcc = *gxp; gxp += 512;
        L1_STEP(hfA, hfB, tt, z0);
        float4 z1 = zcc;
        if (q < 3) { zcc = *gxp; gxp += 512; }
        L1_STEP(hfB, hfA, tt + 1, z1);
      }
    }
#undef L1_STEP

    h2s[(size_t)(b0 + kq) * HDIM + j] = hc;
    c2s[(size_t)(b0 + kq) * HDIM + j] = cc;

    // ---- FC pass over the chunk (after last barrier) ----
    if (ltid < TC * 4) {
      const int tt = ltid >> 2, b = ltid & 3;
      const float bfcv = bfc[0];
      float s0 = 0.f, s1 = 0.f, s2 = 0.f, s3 = 0.f;
#pragma unroll
      for (int q = 0; q < HDIM / 8; ++q) {
        const f16x8 hv = *(const f16x8*)&S1.h2l[tt][b][q * 8];
        const float* wq = &S1.wfl[q * 8];
        s0 += fmaxf((float)hv[0], 0.f) * wq[0];
        s1 += fmaxf((float)hv[1], 0.f) * wq[1];
        s2 += fmaxf((float)hv[2], 0.f) * wq[2];
        s3 += fmaxf((float)hv[3], 0.f) * wq[3];
        s0 += fmaxf((float)hv[4], 0.f) * wq[4];
        s1 += fmaxf((float)hv[5], 0.f) * wq[5];
        s2 += fmaxf((float)hv[6], 0.f) * wq[6];
        s3 += fmaxf((float)hv[7], 0.f) * wq[7];
      }
      const float s = s0 + s1 + s2 + s3 + bfcv;
      out[(size_t)(b0 + b) * T_SEQ + (ch - 1) * TC + tt] = fmaxf(s, 0.0f);
    }
  }
}

extern "C" void kernel_launch(void* const* d_in, const int* in_sizes, int n_in,
                              void* d_out, int out_size, void* d_ws, size_t ws_size,
                              hipStream_t stream)
{
  const float* x    = (const float*)d_in[0];
  const float* Wih0 = (const float*)d_in[1];
  const float* Whh0 = (const float*)d_in[2];
  const float* bih0 = (const float*)d_in[3];
  const float* bhh0 = (const float*)d_in[4];
  const float* Wih1 = (const float*)d_in[5];
  const float* Whh1 = (const float*)d_in[6];
  const float* bih1 = (const float*)d_in[7];
  const float* bhh1 = (const float*)d_in[8];
  const float* Wfc  = (const float*)d_in[9];
  const float* bfc  = (const float*)d_in[10];
  float* out = (float*)d_out;

  const size_t stateN = (size_t)NBATCH * HDIM;  // 65536
  float* h1s = (float*)d_ws;
  float* c1s = h1s + stateN;
  float* h2s = c1s + stateN;
  float* c2s = h2s + stateN;
  ushort_t* w0h  = (ushort_t*)(c2s + stateN);
  ushort_t* w0l  = w0h  + stateN;
  ushort_t* w1h  = w0l  + stateN;
  ushort_t* w1l  = w1h  + stateN;
  ushort_t* wi1h = w1l  + stateN;
  ushort_t* wi1l = wi1h + stateN;
  ushort_t* wxh  = wi1l + stateN;
  ushort_t* wxl  = wxh  + 512 * 32;
  ushort_t* h1buf = wxl + 512 * 32;                       // 2*NWGH*TC*4*HDIM fp16
  float* gx1buf = (float*)(h1buf + (size_t)2 * NWGH * TC * 4 * HDIM);

  // zero-init recurrent states (h0 = c0 = 0)
  (void)hipMemsetAsync(d_ws, 0, 4 * stateN * sizeof(float), stream);
  hipLaunchKernelGGL(prep_weights, dim3(256), dim3(256), 0, stream,
                     Whh0, Whh1, Wih0, Wih1,
                     w0h, w0l, w1h, w1l, wxh, wxl, wi1h, wi1l);

  for (int ch = 0; ch <= NCHUNK; ++ch) {
    hipLaunchKernelGGL(lstm_pipe, dim3(NWGH), dim3(1024), 0, stream,
                       x, w0h, wxh, wxl, bih0, bhh0,
                       wi1h, w1h, bih1, bhh1, Wfc, bfc,
                       out, h1s, c1s, h2s, c2s, h1buf, gx1buf, ch);
  }
}

// Round 18
// 1806.515 us; speedup vs baseline: 1.2582x; 1.2582x over previous
//
#include <hip/hip_runtime.h>

#define T_SEQ  1024
#define NBATCH 512
#define IN_DIM 16
#define HDIM   128
#define G4     (4 * HDIM)
#define TC     64
#define NCHUNK (T_SEQ / TC)
#define NWGH   64   // WGs per role; 8 batches per WG (two independent groups)

typedef unsigned short ushort_t;
typedef __attribute__((ext_vector_type(8))) _Float16 f16x8;
typedef __attribute__((ext_vector_type(4))) float f32x4;

#define MFMA16(a, b, c) __builtin_amdgcn_mfma_f32_16x16x32_f16((a), (b), (c), 0, 0, 0)

__device__ __forceinline__ float sigf(float x) {
  return __builtin_amdgcn_rcpf(1.0f + __expf(-x));
}
__device__ __forceinline__ float tanhf_fast(float x) {
  return 1.0f - 2.0f * __builtin_amdgcn_rcpf(1.0f + __expf(2.0f * x));
}
__device__ __forceinline__ ushort_t f16_bits(float f) {
  const _Float16 h = (_Float16)f;
  return __builtin_bit_cast(unsigned short, h);
}
__device__ __forceinline__ void split_f16(float f, ushort_t* hi, ushort_t* lo) {
  const _Float16 h = (_Float16)f;
  *hi = __builtin_bit_cast(unsigned short, h);
  const _Float16 l = (_Float16)(f - (float)h);
  *lo = __builtin_bit_cast(unsigned short, l);
}
// barrier that waits only on LDS ops (global stores stay in flight)
__device__ __forceinline__ void bar_lds() {
  asm volatile("s_waitcnt lgkmcnt(0)\n\ts_barrier" ::: "memory");
}

// ---------------- prep: split weights into fp16 hi/lo ----------------
__global__ __launch_bounds__(256) void prep_weights(
    const float* __restrict__ Whh0, const float* __restrict__ Whh1,
    const float* __restrict__ Wih0, const float* __restrict__ Wih1,
    ushort_t* __restrict__ w0h, ushort_t* __restrict__ w0l,
    ushort_t* __restrict__ w1h, ushort_t* __restrict__ w1l,
    ushort_t* __restrict__ wxh, ushort_t* __restrict__ wxl,
    ushort_t* __restrict__ wi1h, ushort_t* __restrict__ wi1l)
{
  const int idx = blockIdx.x * 256 + threadIdx.x;
  if (idx < 512 * HDIM) {
    split_f16(Whh0[idx], &w0h[idx], &w0l[idx]);
    split_f16(Whh1[idx], &w1h[idx], &w1l[idx]);
    split_f16(Wih1[idx], &wi1h[idx], &wi1l[idx]);
  }
  if (idx < 512 * 32) {  // Wih0 zero-padded K=16 -> 32
    const int g = idx >> 5, k = idx & 31;
    const float f = (k < IN_DIM) ? Wih0[g * IN_DIM + k] : 0.0f;
    split_f16(f, &wxh[idx], &wxl[idx]);
  }
}

struct L0LDS {
  __align__(16) ushort_t hfA[8][144];
  __align__(16) ushort_t hfB[8][144];
  __align__(16) ushort_t xlds[8][TC][32];
  __align__(16) float gx0s[4 * 8 * 128 * 4];  // [t_local][gb][j][gate], 64 KB
};
struct L1LDS {
  __align__(16) ushort_t hfA[8][144];
  __align__(16) ushort_t hfB[8][144];
  __align__(16) float wfl[HDIM];
};

// ---------------- pipelined launch, dual-group waves ----------------
// l0(ch) on WGs [0,64), gemm+l1(ch-1) on WGs [64,128). Each WG owns 8
// batches as TWO independent 4-batch groups; the groups' MFMA/update
// chains interleave inside each wave, hiding the serial-step latency.
// Weight fragments are shared between groups (no VGPR doubling). Gate
// cols permuted (g = i*128 + wv*16 + row); A rows carry batch = row>>2
// within a group -> in-lane update on all 64 lanes (one batch per lane
// per group). Recurrent/gx1 W terms fp16-hi only (validated R14-R16);
// x-path keeps hi+lo. Sub-chunks of 4 steps; h2 staged to global h2buf,
// FC pass at chunk end (512 independent (t,b) rows).
__global__ __launch_bounds__(512, 2) void lstm_pipe(
    const float* __restrict__ x,
    const ushort_t* __restrict__ w0h,
    const ushort_t* __restrict__ wxh, const ushort_t* __restrict__ wxl,
    const float* __restrict__ bih0, const float* __restrict__ bhh0,
    const ushort_t* __restrict__ wi1h,
    const ushort_t* __restrict__ w1h,
    const float* __restrict__ bih1, const float* __restrict__ bhh1,
    const float* __restrict__ Wfc, const float* __restrict__ bfc,
    float* __restrict__ out,
    float* __restrict__ h1s, float* __restrict__ c1s,
    float* __restrict__ h2s, float* __restrict__ c2s,
    ushort_t* __restrict__ h1buf,   // [2][NWGH][TC*8][HDIM] fp16
    ushort_t* __restrict__ h2buf,   // [NWGH][TC*8][HDIM] fp16
    float* __restrict__ gx1buf,     // [NWGH][TC*8][HDIM][4]
    int ch)
{
  const int tid  = threadIdx.x;
  const int lane = tid & 63;
  const int wv   = tid >> 6;
  const int row  = lane & 15;
  const int kq   = lane >> 4;    // update-phase batch (within group)
  const int bq   = row >> 2;     // A-fragment batch (within group)
  const int j    = wv * 16 + row;

  __shared__ L0LDS S0;
  __shared__ L1LDS S1;

  if (blockIdx.x < NWGH) {
    // ================= L0 ROLE: chunk ch, 8 batches =================
    if (ch >= NCHUNK) return;
    const int w  = blockIdx.x;
    const int b0 = w * 8;

    f16x8 Bh[4][4], Bxh[4], Bxl[4];
#pragma unroll
    for (int i = 0; i < 4; ++i) {
      const int g = i * 128 + j;
#pragma unroll
      for (int kt = 0; kt < 4; ++kt)
        Bh[i][kt] = *(const f16x8*)&w0h[g * HDIM + kt * 32 + kq * 8];
      Bxh[i] = *(const f16x8*)&wxh[g * 32 + kq * 8];
      Bxl[i] = *(const f16x8*)&wxl[g * 32 + kq * 8];
    }

    // stage this chunk's x as fp16: 8 batches x TC x 2 halves = 1024 tasks
#pragma unroll
    for (int q = 0; q < 2; ++q) {
      const int idx  = q * 512 + tid;
      const int half = idx & 1;
      const int ts   = (idx >> 1) & (TC - 1);
      const int b    = idx >> 7;
      const float* src =
          &x[((size_t)(b0 + b) * T_SEQ + ch * TC + ts) * IN_DIM + half * 8];
      const float4 v0 = *(const float4*)&src[0];
      const float4 v1 = *(const float4*)&src[4];
      ushort_t* dst = &S0.xlds[b][ts][half * 8];
      dst[0] = f16_bits(v0.x); dst[1] = f16_bits(v0.y);
      dst[2] = f16_bits(v0.z); dst[3] = f16_bits(v0.w);
      dst[4] = f16_bits(v1.x); dst[5] = f16_bits(v1.y);
      dst[6] = f16_bits(v1.z); dst[7] = f16_bits(v1.w);
      *(float4*)&S0.xlds[b][ts][16 + half * 8] = (float4){0.f, 0.f, 0.f, 0.f};
    }

    float bz[4];
#pragma unroll
    for (int i = 0; i < 4; ++i) bz[i] = bih0[i * 128 + j] + bhh0[i * 128 + j];
    float hc0 = h1s[(size_t)(b0 + kq) * HDIM + j];
    float cc0 = c1s[(size_t)(b0 + kq) * HDIM + j];
    float hc1 = h1s[(size_t)(b0 + 4 + kq) * HDIM + j];
    float cc1 = c1s[(size_t)(b0 + 4 + kq) * HDIM + j];
    S0.hfA[kq][j]     = f16_bits(hc0);
    S0.hfA[4 + kq][j] = f16_bits(hc1);
    __syncthreads();

    ushort_t* hbp = h1buf + ((size_t)(ch & 1) * NWGH + w) * (TC * 8 * HDIM) +
                    (size_t)kq * HDIM + j;

#define L0_STEP(HIN, HOUT, TT)                                              \
  {                                                                         \
    const float4 z0 =                                                       \
        *(const float4*)&S0.gx0s[((((TT) & 3) * 8 + kq) * 128 + j) * 4];    \
    const float4 z1 =                                                       \
        *(const float4*)&S0.gx0s[((((TT) & 3) * 8 + 4 + kq) * 128 + j) * 4];\
    f32x4 a0[4], a1[4];                                                     \
    _Pragma("unroll") for (int i = 0; i < 4; ++i) {                         \
      a0[i] = (f32x4){0.f, 0.f, 0.f, 0.f};                                  \
      a1[i] = (f32x4){0.f, 0.f, 0.f, 0.f};                                  \
    }                                                                       \
    _Pragma("unroll") for (int kt = 0; kt < 4; ++kt) {                      \
      const f16x8 ah0 = *(const f16x8*)&S0.HIN[bq][kt * 32 + kq * 8];       \
      const f16x8 ah1 = *(const f16x8*)&S0.HIN[4 + bq][kt * 32 + kq * 8];   \
      _Pragma("unroll") for (int i = 0; i < 4; ++i)                         \
          a0[i] = MFMA16(ah0, Bh[i][kt], a0[i]);                            \
      _Pragma("unroll") for (int i = 0; i < 4; ++i)                         \
          a1[i] = MFMA16(ah1, Bh[i][kt], a1[i]);                            \
    }                                                                       \
    {                                                                       \
      const float ig = sigf(a0[0][0] + z0.x);                               \
      const float fg = sigf(a0[1][0] + z0.y);                               \
      const float gg = tanhf_fast(a0[2][0] + z0.z);                         \
      const float og = sigf(a0[3][0] + z0.w);                               \
      cc0 = fg * cc0 + ig * gg;                                             \
      hc0 = og * tanhf_fast(cc0);                                           \
      const ushort_t hb0 = f16_bits(hc0);                                   \
      S0.HOUT[kq][j] = hb0;                                                 \
      hbp[0] = hb0;                                                         \
    }                                                                       \
    {                                                                       \
      const float ig = sigf(a1[0][0] + z1.x);                               \
      const float fg = sigf(a1[1][0] + z1.y);                               \
      const float gg = tanhf_fast(a1[2][0] + z1.z);                         \
      const float og = sigf(a1[3][0] + z1.w);                               \
      cc1 = fg * cc1 + ig * gg;                                             \
      hc1 = og * tanhf_fast(cc1);                                           \
      const ushort_t hb1 = f16_bits(hc1);                                   \
      S0.HOUT[4 + kq][j] = hb1;                                             \
      hbp[4 * HDIM] = hb1;                                                  \
    }                                                                       \
    hbp += 8 * HDIM;                                                        \
    bar_lds();                                                              \
  }

    for (int sc = 0; sc < TC / 4; ++sc) {
      // ---- sub-chunk x-GEMM (hi+lo): 4 steps x 8 batches -> LDS gx0s ----
#pragma unroll
      for (int g = 0; g < 2; ++g) {
        const f16x8 a = *(const f16x8*)
            &S0.xlds[g * 4 + (row & 3)][sc * 4 + (row >> 2)][kq * 8];
        f32x4 acc[4];
#pragma unroll
        for (int i = 0; i < 4; ++i) acc[i] = (f32x4){0.f, 0.f, 0.f, 0.f};
#pragma unroll
        for (int i = 0; i < 4; ++i) acc[i] = MFMA16(a, Bxh[i], acc[i]);
#pragma unroll
        for (int i = 0; i < 4; ++i) acc[i] = MFMA16(a, Bxl[i], acc[i]);
#pragma unroll
        for (int r = 0; r < 4; ++r) {
          float4 o;
          o.x = acc[0][r] + bz[0];
          o.y = acc[1][r] + bz[1];
          o.z = acc[2][r] + bz[2];
          o.w = acc[3][r] + bz[3];
          *(float4*)&S0.gx0s[((kq * 8 + g * 4 + r) * 128 + j) * 4] = o;
        }
      }
      bar_lds();
      const int t0s = sc * 4;
      L0_STEP(hfA, hfB, t0s);
      L0_STEP(hfB, hfA, t0s + 1);
      L0_STEP(hfA, hfB, t0s + 2);
      L0_STEP(hfB, hfA, t0s + 3);
    }
#undef L0_STEP

    h1s[(size_t)(b0 + kq) * HDIM + j]     = hc0;
    c1s[(size_t)(b0 + kq) * HDIM + j]     = cc0;
    h1s[(size_t)(b0 + 4 + kq) * HDIM + j] = hc1;
    c1s[(size_t)(b0 + 4 + kq) * HDIM + j] = cc1;
  } else {
    // ================= L1 ROLE: gemm + recurrence, chunk ch-1 =============
    if (ch == 0) return;
    const int w  = blockIdx.x - NWGH;
    const int b0 = w * 8;

    const ushort_t* hb =
        h1buf + ((size_t)((ch - 1) & 1) * NWGH + w) * (TC * 8 * HDIM);
    float* gx = gx1buf + (size_t)w * (TC * 8 * HDIM * 4);
    ushort_t* h2p = h2buf + (size_t)w * (TC * 8 * HDIM) +
                    (size_t)kq * HDIM + j;

    if (tid < HDIM) S1.wfl[tid] = Wfc[tid];

    float bz1[4];
#pragma unroll
    for (int i = 0; i < 4; ++i) bz1[i] = bih1[i * 128 + j] + bhh1[i * 128 + j];
    f16x8 Rh[4][4], Gh[4][4];
#pragma unroll
    for (int i = 0; i < 4; ++i) {
      const int g = i * 128 + j;
#pragma unroll
      for (int kt = 0; kt < 4; ++kt) {
        Rh[i][kt] = *(const f16x8*)&w1h[g * HDIM + kt * 32 + kq * 8];
        Gh[i][kt] = *(const f16x8*)&wi1h[g * HDIM + kt * 32 + kq * 8];
      }
    }

    float hc0 = h2s[(size_t)(b0 + kq) * HDIM + j];
    float cc0 = c2s[(size_t)(b0 + kq) * HDIM + j];
    float hc1 = h2s[(size_t)(b0 + 4 + kq) * HDIM + j];
    float cc1 = c2s[(size_t)(b0 + 4 + kq) * HDIM + j];
    S1.hfA[kq][j]     = f16_bits(hc0);
    S1.hfA[4 + kq][j] = f16_bits(hc1);
    __syncthreads();

#define L1_STEP(HIN, HOUT, TT, Z0, Z1)                                      \
  {                                                                         \
    f32x4 a0[4], a1[4];                                                     \
    _Pragma("unroll") for (int i = 0; i < 4; ++i) {                         \
      a0[i] = (f32x4){0.f, 0.f, 0.f, 0.f};                                  \
      a1[i] = (f32x4){0.f, 0.f, 0.f, 0.f};                                  \
    }                                                                       \
    _Pragma("unroll") for (int kt = 0; kt < 4; ++kt) {                      \
      const f16x8 ah0 = *(const f16x8*)&S1.HIN[bq][kt * 32 + kq * 8];       \
      const f16x8 ah1 = *(const f16x8*)&S1.HIN[4 + bq][kt * 32 + kq * 8];   \
      _Pragma("unroll") for (int i = 0; i < 4; ++i)                         \
          a0[i] = MFMA16(ah0, Rh[i][kt], a0[i]);                            \
      _Pragma("unroll") for (int i = 0; i < 4; ++i)                         \
          a1[i] = MFMA16(ah1, Rh[i][kt], a1[i]);                            \
    }                                                                       \
    {                                                                       \
      const float ig = sigf(a0[0][0] + (Z0).x);                             \
      const float fg = sigf(a0[1][0] + (Z0).y);                             \
      const float gg = tanhf_fast(a0[2][0] + (Z0).z);                       \
      const float og = sigf(a0[3][0] + (Z0).w);                             \
      cc0 = fg * cc0 + ig * gg;                                             \
      hc0 = og * tanhf_fast(cc0);                                           \
      const ushort_t hb0 = f16_bits(hc0);                                   \
      S1.HOUT[kq][j] = hb0;                                                 \
      h2p[0] = hb0;                                                         \
    }                                                                       \
    {                                                                       \
      const float ig = sigf(a1[0][0] + (Z1).x);                             \
      const float fg = sigf(a1[1][0] + (Z1).y);                             \
      const float gg = tanhf_fast(a1[2][0] + (Z1).z);                       \
      const float og = sigf(a1[3][0] + (Z1).w);                             \
      cc1 = fg * cc1 + ig * gg;                                             \
      hc1 = og * tanhf_fast(cc1);                                           \
      const ushort_t hb1 = f16_bits(hc1);                                   \
      S1.HOUT[4 + kq][j] = hb1;                                             \
      h2p[4 * HDIM] = hb1;                                                  \
    }                                                                       \
    h2p += 8 * HDIM;                                                        \
    bar_lds();                                                              \
  }

    for (int sc = 0; sc < TC / 4; ++sc) {
      // ---- sub-chunk gx1 GEMM (hi only): 4 steps x 8 batches ----
#pragma unroll
      for (int g = 0; g < 2; ++g) {
        const f16x8 a = *(const f16x8*)&hb[
            (size_t)((sc * 4 + (row >> 2)) * 8 + g * 4 + (row & 3)) * HDIM +
            0 * 32 + kq * 8];
        f32x4 acc[4];
#pragma unroll
        for (int i = 0; i < 4; ++i) acc[i] = (f32x4){0.f, 0.f, 0.f, 0.f};
#pragma unroll
        for (int kt = 0; kt < 4; ++kt) {
          const f16x8 av = *(const f16x8*)&hb[
              (size_t)((sc * 4 + (row >> 2)) * 8 + g * 4 + (row & 3)) * HDIM +
              kt * 32 + kq * 8];
#pragma unroll
          for (int i = 0; i < 4; ++i) acc[i] = MFMA16(av, Gh[i][kt], acc[i]);
        }
        (void)a;
#pragma unroll
        for (int r = 0; r < 4; ++r) {
          const int m = (sc * 4 + kq) * 8 + g * 4 + r;
          float4 o;
          o.x = acc[0][r] + bz1[0];
          o.y = acc[1][r] + bz1[1];
          o.z = acc[2][r] + bz1[2];
          o.w = acc[3][r] + bz1[3];
          *(float4*)&gx[((size_t)m * 128 + j) * 4] = o;
        }
      }
      __syncthreads();  // vmcnt drain: gx stores visible to step reads

      const float4* zp =
          (const float4*)gx + ((size_t)(sc * 4) * 8 + kq) * 128 + j;
      float4 zc0 = zp[0], zc1 = zp[512];
      zp += 1024;
      const int t0s = sc * 4;
      {
        float4 u0 = zc0, u1 = zc1;
        zc0 = zp[0]; zc1 = zp[512]; zp += 1024;
        L1_STEP(hfA, hfB, t0s, u0, u1);
      }
      {
        float4 u0 = zc0, u1 = zc1;
        zc0 = zp[0]; zc1 = zp[512]; zp += 1024;
        L1_STEP(hfB, hfA, t0s + 1, u0, u1);
      }
      {
        float4 u0 = zc0, u1 = zc1;
        zc0 = zp[0]; zc1 = zp[512];
        L1_STEP(hfA, hfB, t0s + 2, u0, u1);
      }
      L1_STEP(hfB, hfA, t0s + 3, zc0, zc1);
    }
#undef L1_STEP

    h2s[(size_t)(b0 + kq) * HDIM + j]     = hc0;
    c2s[(size_t)(b0 + kq) * HDIM + j]     = cc0;
    h2s[(size_t)(b0 + 4 + kq) * HDIM + j] = hc1;
    c2s[(size_t)(b0 + 4 + kq) * HDIM + j] = cc1;
    __syncthreads();  // drain h2buf stores before FC reads

    // ---- FC pass: 512 threads <-> 512 (t,b) rows of this chunk ----
    {
      const int tt = tid >> 3, b = tid & 7;
      const ushort_t* hrow =
          h2buf + (size_t)w * (TC * 8 * HDIM) + (size_t)tid * HDIM;
      const float bfcv = bfc[0];
      float s0 = 0.f, s1 = 0.f, s2 = 0.f, s3 = 0.f;
#pragma unroll
      for (int q = 0; q < HDIM / 8; ++q) {
        const f16x8 hv = *(const f16x8*)&hrow[q * 8];
        const float* wq = &S1.wfl[q * 8];
        s0 += fmaxf((float)hv[0], 0.f) * wq[0];
        s1 += fmaxf((float)hv[1], 0.f) * wq[1];
        s2 += fmaxf((float)hv[2], 0.f) * wq[2];
        s3 += fmaxf((float)hv[3], 0.f) * wq[3];
        s0 += fmaxf((float)hv[4], 0.f) * wq[4];
        s1 += fmaxf((float)hv[5], 0.f) * wq[5];
        s2 += fmaxf((float)hv[6], 0.f) * wq[6];
        s3 += fmaxf((float)hv[7], 0.f) * wq[7];
      }
      const float s = s0 + s1 + s2 + s3 + bfcv;
      out[(size_t)(b0 + b) * T_SEQ + (ch - 1) * TC + tt] = fmaxf(s, 0.0f);
    }
  }
}

extern "C" void kernel_launch(void* const* d_in, const int* in_sizes, int n_in,
                              void* d_out, int out_size, void* d_ws, size_t ws_size,
                              hipStream_t stream)
{
  const float* x    = (const float*)d_in[0];
  const float* Wih0 = (const float*)d_in[1];
  const float* Whh0 = (const float*)d_in[2];
  const float* bih0 = (const float*)d_in[3];
  const float* bhh0 = (const float*)d_in[4];
  const float* Wih1 = (const float*)d_in[5];
  const float* Whh1 = (const float*)d_in[6];
  const float* bih1 = (const float*)d_in[7];
  const float* bhh1 = (const float*)d_in[8];
  const float* Wfc  = (const float*)d_in[9];
  const float* bfc  = (const float*)d_in[10];
  float* out = (float*)d_out;

  const size_t stateN = (size_t)NBATCH * HDIM;  // 65536
  float* h1s = (float*)d_ws;
  float* c1s = h1s + stateN;
  float* h2s = c1s + stateN;
  float* c2s = h2s + stateN;
  ushort_t* w0h  = (ushort_t*)(c2s + stateN);
  ushort_t* w0l  = w0h  + stateN;
  ushort_t* w1h  = w0l  + stateN;
  ushort_t* w1l  = w1h  + stateN;
  ushort_t* wi1h = w1l  + stateN;
  ushort_t* wi1l = wi1h + stateN;
  ushort_t* wxh  = wi1l + stateN;
  ushort_t* wxl  = wxh  + 512 * 32;
  ushort_t* h1buf = wxl + 512 * 32;   // 2*NWGH*TC*8*HDIM fp16 = 16.8 MB
  ushort_t* h2buf = h1buf + (size_t)2 * NWGH * TC * 8 * HDIM;  // 8.4 MB
  float* gx1buf = (float*)(h2buf + (size_t)NWGH * TC * 8 * HDIM);  // 67 MB

  // zero-init recurrent states (h0 = c0 = 0)
  (void)hipMemsetAsync(d_ws, 0, 4 * stateN * sizeof(float), stream);
  hipLaunchKernelGGL(prep_weights, dim3(256), dim3(256), 0, stream,
                     Whh0, Whh1, Wih0, Wih1,
                     w0h, w0l, w1h, w1l, wxh, wxl, wi1h, wi1l);

  for (int ch = 0; ch <= NCHUNK; ++ch) {
    hipLaunchKernelGGL(lstm_pipe, dim3(2 * NWGH), dim3(512), 0, stream,
                       x, w0h, wxh, wxl, bih0, bhh0,
                       wi1h, w1h, bih1, bhh1, Wfc, bfc,
                       out, h1s, c1s, h2s, c2s, h1buf, h2buf, gx1buf, ch);
  }
}

// Round 19
// 1432.828 us; speedup vs baseline: 1.5864x; 1.2608x over previous
//
#include <hip/hip_runtime.h>

#define T_SEQ  1024
#define NBATCH 512
#define IN_DIM 16
#define HDIM   128
#define G4     (4 * HDIM)
#define TC     64
#define NCHUNK (T_SEQ / TC)
#define NWGH   64   // WGs per role; 8 distinct batches per WG (2x M-redundancy)

typedef unsigned short ushort_t;
typedef __attribute__((ext_vector_type(8))) _Float16 f16x8;
typedef __attribute__((ext_vector_type(4))) float f32x4;

#define MFMA16(a, b, c) __builtin_amdgcn_mfma_f32_16x16x32_f16((a), (b), (c), 0, 0, 0)

__device__ __forceinline__ float sigf(float x) {
  return __builtin_amdgcn_rcpf(1.0f + __expf(-x));
}
__device__ __forceinline__ float tanhf_fast(float x) {
  return 1.0f - 2.0f * __builtin_amdgcn_rcpf(1.0f + __expf(2.0f * x));
}
__device__ __forceinline__ ushort_t f16_bits(float f) {
  const _Float16 h = (_Float16)f;
  return __builtin_bit_cast(unsigned short, h);
}
__device__ __forceinline__ void split_f16(float f, ushort_t* hi, ushort_t* lo) {
  const _Float16 h = (_Float16)f;
  *hi = __builtin_bit_cast(unsigned short, h);
  const _Float16 l = (_Float16)(f - (float)h);
  *lo = __builtin_bit_cast(unsigned short, l);
}
// barrier that waits only on LDS ops (global stores stay in flight)
__device__ __forceinline__ void bar_lds() {
  asm volatile("s_waitcnt lgkmcnt(0)\n\ts_barrier" ::: "memory");
}

// ---------------- prep: split weights into fp16 hi/lo ----------------
__global__ __launch_bounds__(256) void prep_weights(
    const float* __restrict__ Whh0, const float* __restrict__ Whh1,
    const float* __restrict__ Wih0, const float* __restrict__ Wih1,
    ushort_t* __restrict__ w0h, ushort_t* __restrict__ w0l,
    ushort_t* __restrict__ w1h, ushort_t* __restrict__ w1l,
    ushort_t* __restrict__ wxh, ushort_t* __restrict__ wxl,
    ushort_t* __restrict__ wi1h, ushort_t* __restrict__ wi1l)
{
  const int idx = blockIdx.x * 256 + threadIdx.x;
  if (idx < 512 * HDIM) {
    split_f16(Whh0[idx], &w0h[idx], &w0l[idx]);
    split_f16(Whh1[idx], &w1h[idx], &w1l[idx]);
    split_f16(Wih1[idx], &wi1h[idx], &wi1l[idx]);
  }
  if (idx < 512 * 32) {  // Wih0 zero-padded K=16 -> 32
    const int g = idx >> 5, k = idx & 31;
    const float f = (k < IN_DIM) ? Wih0[g * IN_DIM + k] : 0.0f;
    split_f16(f, &wxh[idx], &wxl[idx]);
  }
}

// gate-input LDS buffers: row = t_local*8 + b, padded stride 516 floats
// (b-groups land on distinct banks for the per-step float4 reads)
#define GXS 516

struct L0LDS {
  __align__(16) ushort_t hfA[8][144];
  __align__(16) ushort_t hfB[8][144];
  __align__(16) ushort_t xlds[8][TC][32];
  __align__(16) float gx0s[32 * GXS];   // 4 steps x 8 batches
};
struct L1LDS {
  __align__(16) ushort_t hfA[8][144];
  __align__(16) ushort_t hfB[8][144];
  __align__(16) float gxs[32 * GXS];
  __align__(16) float wfl[HDIM];
};

// ---------------- pipelined launch, 8 distinct batches per WG ----------
// l0(ch) on WGs [0,64), gemm+l1(ch-1) on WGs [64,128). A rows carry batch
// row>>1 (2x duplication instead of R16's 4x): the same 16 recurrent MFMAs
// serve 8 batches. Lane (kq, col j) owns batches kq*2 (acc reg 0) and
// kq*2+1 (acc reg 2): two in-lane updates per lane, all 64 lanes busy.
// gx1 lives in LDS (per-4-step sub-chunks); h2 staged to global h2buf for
// the chunk-end FC (validated R18). Recurrent/gx1 weights fp16-hi only
// (validated R14-R16); x-path hi+lo.
__global__ __launch_bounds__(512, 2) void lstm_pipe(
    const float* __restrict__ x,
    const ushort_t* __restrict__ w0h,
    const ushort_t* __restrict__ wxh, const ushort_t* __restrict__ wxl,
    const float* __restrict__ bih0, const float* __restrict__ bhh0,
    const ushort_t* __restrict__ wi1h,
    const ushort_t* __restrict__ w1h,
    const float* __restrict__ bih1, const float* __restrict__ bhh1,
    const float* __restrict__ Wfc, const float* __restrict__ bfc,
    float* __restrict__ out,
    float* __restrict__ h1s, float* __restrict__ c1s,
    float* __restrict__ h2s, float* __restrict__ c2s,
    ushort_t* __restrict__ h1buf,   // [2][NWGH][TC*8][HDIM] fp16
    ushort_t* __restrict__ h2buf,   // [NWGH][TC*8][HDIM] fp16
    int ch)
{
  const int tid  = threadIdx.x;
  const int lane = tid & 63;
  const int wv   = tid >> 6;
  const int row  = lane & 15;
  const int kq   = lane >> 4;
  const int bq   = row >> 1;      // A-fragment batch for this lane's A row
  const int ub0  = kq * 2;        // first update batch owned by this lane
  const int j    = wv * 16 + row;

  constexpr size_t POOL =
      sizeof(L0LDS) > sizeof(L1LDS) ? sizeof(L0LDS) : sizeof(L1LDS);
  __shared__ __align__(16) char pool[POOL];

  if (blockIdx.x < NWGH) {
    // ================= L0 ROLE: chunk ch, 8 batches =================
    if (ch >= NCHUNK) return;
    L0LDS& S = *(L0LDS*)pool;
    const int w  = blockIdx.x;
    const int b0 = w * 8;

    f16x8 Bh[4][4];
#pragma unroll
    for (int i = 0; i < 4; ++i) {
      const int g = i * 128 + j;
#pragma unroll
      for (int kt = 0; kt < 4; ++kt)
        Bh[i][kt] = *(const f16x8*)&w0h[g * HDIM + kt * 32 + kq * 8];
    }

    // stage this chunk's x as fp16: 8 batches x TC x 2 halves = 1024 tasks
#pragma unroll
    for (int q = 0; q < 2; ++q) {
      const int idx  = q * 512 + tid;
      const int half = idx & 1;
      const int ts   = (idx >> 1) & (TC - 1);
      const int b    = idx >> 7;
      const float* src =
          &x[((size_t)(b0 + b) * T_SEQ + ch * TC + ts) * IN_DIM + half * 8];
      const float4 v0 = *(const float4*)&src[0];
      const float4 v1 = *(const float4*)&src[4];
      ushort_t* dst = &S.xlds[b][ts][half * 8];
      dst[0] = f16_bits(v0.x); dst[1] = f16_bits(v0.y);
      dst[2] = f16_bits(v0.z); dst[3] = f16_bits(v0.w);
      dst[4] = f16_bits(v1.x); dst[5] = f16_bits(v1.y);
      dst[6] = f16_bits(v1.z); dst[7] = f16_bits(v1.w);
      *(float4*)&S.xlds[b][ts][16 + half * 8] = (float4){0.f, 0.f, 0.f, 0.f};
    }

    float bz[4];
#pragma unroll
    for (int i = 0; i < 4; ++i) bz[i] = bih0[i * 128 + j] + bhh0[i * 128 + j];
    float hc0 = h1s[(size_t)(b0 + ub0) * HDIM + j];
    float cc0 = c1s[(size_t)(b0 + ub0) * HDIM + j];
    float hc1 = h1s[(size_t)(b0 + ub0 + 1) * HDIM + j];
    float cc1 = c1s[(size_t)(b0 + ub0 + 1) * HDIM + j];
    S.hfA[ub0][j]     = f16_bits(hc0);
    S.hfA[ub0 + 1][j] = f16_bits(hc1);
    __syncthreads();

    ushort_t* hbp = h1buf + ((size_t)(ch & 1) * NWGH + w) * (TC * 8 * HDIM) +
                    (size_t)ub0 * HDIM + j;

#define L0_STEP(HIN, HOUT, TT)                                              \
  {                                                                         \
    const float4 z0 =                                                       \
        *(const float4*)&S.gx0s[(((TT) & 3) * 8 + ub0) * GXS + j * 4];      \
    const float4 z1 =                                                       \
        *(const float4*)&S.gx0s[(((TT) & 3) * 8 + ub0 + 1) * GXS + j * 4];  \
    f32x4 aH[4];                                                            \
    _Pragma("unroll") for (int i = 0; i < 4; ++i)                           \
        aH[i] = (f32x4){0.f, 0.f, 0.f, 0.f};                                \
    _Pragma("unroll") for (int kt = 0; kt < 4; ++kt) {                      \
      const f16x8 ah = *(const f16x8*)&S.HIN[bq][kt * 32 + kq * 8];         \
      _Pragma("unroll") for (int i = 0; i < 4; ++i)                         \
          aH[i] = MFMA16(ah, Bh[i][kt], aH[i]);                             \
    }                                                                       \
    {                                                                       \
      const float ig = sigf(aH[0][0] + z0.x);                               \
      const float fg = sigf(aH[1][0] + z0.y);                               \
      const float gg = tanhf_fast(aH[2][0] + z0.z);                         \
      const float og = sigf(aH[3][0] + z0.w);                               \
      cc0 = fg * cc0 + ig * gg;                                             \
      hc0 = og * tanhf_fast(cc0);                                           \
      const ushort_t hb0 = f16_bits(hc0);                                   \
      S.HOUT[ub0][j] = hb0;                                                 \
      hbp[0] = hb0;                                                         \
    }                                                                       \
    {                                                                       \
      const float ig = sigf(aH[0][2] + z1.x);                               \
      const float fg = sigf(aH[1][2] + z1.y);                               \
      const float gg = tanhf_fast(aH[2][2] + z1.z);                         \
      const float og = sigf(aH[3][2] + z1.w);                               \
      cc1 = fg * cc1 + ig * gg;                                             \
      hc1 = og * tanhf_fast(cc1);                                           \
      const ushort_t hb1 = f16_bits(hc1);                                   \
      S.HOUT[ub0 + 1][j] = hb1;                                             \
      hbp[HDIM] = hb1;                                                      \
    }                                                                       \
    hbp += 8 * HDIM;                                                        \
    bar_lds();                                                              \
  }

    for (int sc = 0; sc < TC / 4; ++sc) {
      // ---- sub-chunk x-GEMM (hi+lo): 4 steps x 8 batches -> LDS gx0s ----
      // M-tile rows r = t*8+b (t = r>>3 within tile, b = r&7)
      {
        f16x8 Bxh[4], Bxl[4];
#pragma unroll
        for (int i = 0; i < 4; ++i) {
          const int g = i * 128 + j;
          Bxh[i] = *(const f16x8*)&wxh[g * 32 + kq * 8];
          Bxl[i] = *(const f16x8*)&wxl[g * 32 + kq * 8];
        }
#pragma unroll
        for (int mt = 0; mt < 2; ++mt) {
          const f16x8 a = *(const f16x8*)
              &S.xlds[row & 7][sc * 4 + mt * 2 + (row >> 3)][kq * 8];
          f32x4 acc[4];
#pragma unroll
          for (int i = 0; i < 4; ++i) acc[i] = (f32x4){0.f, 0.f, 0.f, 0.f};
#pragma unroll
          for (int i = 0; i < 4; ++i) acc[i] = MFMA16(a, Bxh[i], acc[i]);
#pragma unroll
          for (int i = 0; i < 4; ++i) acc[i] = MFMA16(a, Bxl[i], acc[i]);
          // C row m = kq*4+r -> t = mt*2 + (kq>>1), b = (kq&1)*4 + r
          const int t8 = (mt * 2 + (kq >> 1)) * 8 + (kq & 1) * 4;
#pragma unroll
          for (int r = 0; r < 4; ++r) {
            float4 o;
            o.x = acc[0][r] + bz[0];
            o.y = acc[1][r] + bz[1];
            o.z = acc[2][r] + bz[2];
            o.w = acc[3][r] + bz[3];
            *(float4*)&S.gx0s[(t8 + r) * GXS + j * 4] = o;
          }
        }
      }
      bar_lds();
      const int t0s = sc * 4;
      L0_STEP(hfA, hfB, t0s);
      L0_STEP(hfB, hfA, t0s + 1);
      L0_STEP(hfA, hfB, t0s + 2);
      L0_STEP(hfB, hfA, t0s + 3);
    }
#undef L0_STEP

    h1s[(size_t)(b0 + ub0) * HDIM + j]     = hc0;
    c1s[(size_t)(b0 + ub0) * HDIM + j]     = cc0;
    h1s[(size_t)(b0 + ub0 + 1) * HDIM + j] = hc1;
    c1s[(size_t)(b0 + ub0 + 1) * HDIM + j] = cc1;
  } else {
    // ================= L1 ROLE: gemm + recurrence, chunk ch-1 =============
    if (ch == 0) return;
    L1LDS& S = *(L1LDS*)pool;
    const int w  = blockIdx.x - NWGH;
    const int b0 = w * 8;

    const ushort_t* hb =
        h1buf + ((size_t)((ch - 1) & 1) * NWGH + w) * (TC * 8 * HDIM);
    ushort_t* h2p = h2buf + (size_t)w * (TC * 8 * HDIM) +
                    (size_t)ub0 * HDIM + j;

    if (tid < HDIM) S.wfl[tid] = Wfc[tid];

    float bz1[4];
#pragma unroll
    for (int i = 0; i < 4; ++i) bz1[i] = bih1[i * 128 + j] + bhh1[i * 128 + j];
    f16x8 Rh[4][4];
#pragma unroll
    for (int i = 0; i < 4; ++i) {
      const int g = i * 128 + j;
#pragma unroll
      for (int kt = 0; kt < 4; ++kt)
        Rh[i][kt] = *(const f16x8*)&w1h[g * HDIM + kt * 32 + kq * 8];
    }

    float hc0 = h2s[(size_t)(b0 + ub0) * HDIM + j];
    float cc0 = c2s[(size_t)(b0 + ub0) * HDIM + j];
    float hc1 = h2s[(size_t)(b0 + ub0 + 1) * HDIM + j];
    float cc1 = c2s[(size_t)(b0 + ub0 + 1) * HDIM + j];
    S.hfA[ub0][j]     = f16_bits(hc0);
    S.hfA[ub0 + 1][j] = f16_bits(hc1);
    __syncthreads();

#define L1_STEP(HIN, HOUT, TT)                                              \
  {                                                                         \
    const float4 z0 =                                                       \
        *(const float4*)&S.gxs[(((TT) & 3) * 8 + ub0) * GXS + j * 4];       \
    const float4 z1 =                                                       \
        *(const float4*)&S.gxs[(((TT) & 3) * 8 + ub0 + 1) * GXS + j * 4];   \
    f32x4 aH[4];                                                            \
    _Pragma("unroll") for (int i = 0; i < 4; ++i)                           \
        aH[i] = (f32x4){0.f, 0.f, 0.f, 0.f};                                \
    _Pragma("unroll") for (int kt = 0; kt < 4; ++kt) {                      \
      const f16x8 ah = *(const f16x8*)&S.HIN[bq][kt * 32 + kq * 8];         \
      _Pragma("unroll") for (int i = 0; i < 4; ++i)                         \
          aH[i] = MFMA16(ah, Rh[i][kt], aH[i]);                             \
    }                                                                       \
    {                                                                       \
      const float ig = sigf(aH[0][0] + z0.x);                               \
      const float fg = sigf(aH[1][0] + z0.y);                               \
      const float gg = tanhf_fast(aH[2][0] + z0.z);                         \
      const float og = sigf(aH[3][0] + z0.w);                               \
      cc0 = fg * cc0 + ig * gg;                                             \
      hc0 = og * tanhf_fast(cc0);                                           \
      const ushort_t hb0 = f16_bits(hc0);                                   \
      S.HOUT[ub0][j] = hb0;                                                 \
      h2p[0] = hb0;                                                         \
    }                                                                       \
    {                                                                       \
      const float ig = sigf(aH[0][2] + z1.x);                               \
      const float fg = sigf(aH[1][2] + z1.y);                               \
      const float gg = tanhf_fast(aH[2][2] + z1.z);                         \
      const float og = sigf(aH[3][2] + z1.w);                               \
      cc1 = fg * cc1 + ig * gg;                                             \
      hc1 = og * tanhf_fast(cc1);                                           \
      const ushort_t hb1 = f16_bits(hc1);                                   \
      S.HOUT[ub0 + 1][j] = hb1;                                             \
      h2p[HDIM] = hb1;                                                      \
    }                                                                       \
    h2p += 8 * HDIM;                                                        \
    bar_lds();                                                              \
  }

    for (int sc = 0; sc < TC / 4; ++sc) {
      // ---- sub-chunk gx1 GEMM (hi only), N in half-tiles (reg pressure) --
#pragma unroll
      for (int half = 0; half < 2; ++half) {
        f16x8 Gh[2][4];
#pragma unroll
        for (int i2 = 0; i2 < 2; ++i2) {
          const int g = (half * 2 + i2) * 128 + j;
#pragma unroll
          for (int kt = 0; kt < 4; ++kt)
            Gh[i2][kt] = *(const f16x8*)&wi1h[g * HDIM + kt * 32 + kq * 8];
        }
#pragma unroll
        for (int mt = 0; mt < 2; ++mt) {
          f32x4 acc[2];
          acc[0] = (f32x4){0.f, 0.f, 0.f, 0.f};
          acc[1] = (f32x4){0.f, 0.f, 0.f, 0.f};
#pragma unroll
          for (int kt = 0; kt < 4; ++kt) {
            const f16x8 a = *(const f16x8*)&hb[
                (size_t)((sc * 4 + mt * 2 + (row >> 3)) * 8 + (row & 7)) * HDIM +
                kt * 32 + kq * 8];
            acc[0] = MFMA16(a, Gh[0][kt], acc[0]);
            acc[1] = MFMA16(a, Gh[1][kt], acc[1]);
          }
          const int t8 = (mt * 2 + (kq >> 1)) * 8 + (kq & 1) * 4;
#pragma unroll
          for (int r = 0; r < 4; ++r) {
            float2 o;
            o.x = acc[0][r] + bz1[half * 2];
            o.y = acc[1][r] + bz1[half * 2 + 1];
            *(float2*)&S.gxs[(t8 + r) * GXS + j * 4 + half * 2] = o;
          }
        }
      }
      bar_lds();
      const int t0s = sc * 4;
      L1_STEP(hfA, hfB, t0s);
      L1_STEP(hfB, hfA, t0s + 1);
      L1_STEP(hfA, hfB, t0s + 2);
      L1_STEP(hfB, hfA, t0s + 3);
    }
#undef L1_STEP

    h2s[(size_t)(b0 + ub0) * HDIM + j]     = hc0;
    c2s[(size_t)(b0 + ub0) * HDIM + j]     = cc0;
    h2s[(size_t)(b0 + ub0 + 1) * HDIM + j] = hc1;
    c2s[(size_t)(b0 + ub0 + 1) * HDIM + j] = cc1;
    __syncthreads();  // drain h2buf stores before FC reads

    // ---- FC pass: 512 threads <-> 512 (t,b) rows of this chunk ----
    {
      const int tt = tid >> 3, b = tid & 7;
      const ushort_t* hrow =
          h2buf + (size_t)w * (TC * 8 * HDIM) + (size_t)tid * HDIM;
      const float bfcv = bfc[0];
      float s0 = 0.f, s1 = 0.f, s2 = 0.f, s3 = 0.f;
#pragma unroll
      for (int q = 0; q < HDIM / 8; ++q) {
        const f16x8 hv = *(const f16x8*)&hrow[q * 8];
        const float* wq = &S.wfl[q * 8];
        s0 += fmaxf((float)hv[0], 0.f) * wq[0];
        s1 += fmaxf((float)hv[1], 0.f) * wq[1];
        s2 += fmaxf((float)hv[2], 0.f) * wq[2];
        s3 += fmaxf((float)hv[3], 0.f) * wq[3];
        s0 += fmaxf((float)hv[4], 0.f) * wq[4];
        s1 += fmaxf((float)hv[5], 0.f) * wq[5];
        s2 += fmaxf((float)hv[6], 0.f) * wq[6];
        s3 += fmaxf((float)hv[7], 0.f) * wq[7];
      }
      const float s = s0 + s1 + s2 + s3 + bfcv;
      out[(size_t)(b0 + b) * T_SEQ + (ch - 1) * TC + tt] = fmaxf(s, 0.0f);
    }
  }
}

extern "C" void kernel_launch(void* const* d_in, const int* in_sizes, int n_in,
                              void* d_out, int out_size, void* d_ws, size_t ws_size,
                              hipStream_t stream)
{
  const float* x    = (const float*)d_in[0];
  const float* Wih0 = (const float*)d_in[1];
  const float* Whh0 = (const float*)d_in[2];
  const float* bih0 = (const float*)d_in[3];
  const float* bhh0 = (const float*)d_in[4];
  const float* Wih1 = (const float*)d_in[5];
  const float* Whh1 = (const float*)d_in[6];
  const float* bih1 = (const float*)d_in[7];
  const float* bhh1 = (const float*)d_in[8];
  const float* Wfc  = (const float*)d_in[9];
  const float* bfc  = (const float*)d_in[10];
  float* out = (float*)d_out;

  const size_t stateN = (size_t)NBATCH * HDIM;  // 65536
  float* h1s = (float*)d_ws;
  float* c1s = h1s + stateN;
  float* h2s = c1s + stateN;
  float* c2s = h2s + stateN;
  ushort_t* w0h  = (ushort_t*)(c2s + stateN);
  ushort_t* w0l  = w0h  + stateN;
  ushort_t* w1h  = w0l  + stateN;
  ushort_t* w1l  = w1h  + stateN;
  ushort_t* wi1h = w1l  + stateN;
  ushort_t* wi1l = wi1h + stateN;
  ushort_t* wxh  = wi1l + stateN;
  ushort_t* wxl  = wxh  + 512 * 32;
  ushort_t* h1buf = wxl + 512 * 32;   // 2*NWGH*TC*8*HDIM fp16 = 16.8 MB
  ushort_t* h2buf = h1buf + (size_t)2 * NWGH * TC * 8 * HDIM;  // 8.4 MB

  // zero-init recurrent states (h0 = c0 = 0)
  (void)hipMemsetAsync(d_ws, 0, 4 * stateN * sizeof(float), stream);
  hipLaunchKernelGGL(prep_weights, dim3(256), dim3(256), 0, stream,
                     Whh0, Whh1, Wih0, Wih1,
                     w0h, w0l, w1h, w1l, wxh, wxl, wi1h, wi1l);

  for (int ch = 0; ch <= NCHUNK; ++ch) {
    hipLaunchKernelGGL(lstm_pipe, dim3(2 * NWGH), dim3(512), 0, stream,
                       x, w0h, wxh, wxl, bih0, bhh0,
                       wi1h, w1h, bih1, bhh1, Wfc, bfc,
                       out, h1s, c1s, h2s, c2s, h1buf, h2buf, ch);
  }
}

// Round 21
// 958.885 us; speedup vs baseline: 2.3704x; 1.4943x over previous
//
#include <hip/hip_runtime.h>

#define T_SEQ  1024
#define NBATCH 512
#define IN_DIM 16
#define HDIM   128
#define G4     (4 * HDIM)
#define TC     64
#define NCHUNK (T_SEQ / TC)
#define NWGH   128   // WGs per role; 4 batches per WG

typedef unsigned short ushort_t;
typedef __attribute__((ext_vector_type(8))) _Float16 f16x8;
typedef __attribute__((ext_vector_type(4))) float f32x4;

#define MFMA16(a, b, c) __builtin_amdgcn_mfma_f32_16x16x32_f16((a), (b), (c), 0, 0, 0)

__device__ __forceinline__ float sigf(float x) {
  return __builtin_amdgcn_rcpf(1.0f + __expf(-x));
}
__device__ __forceinline__ float tanhf_fast(float x) {
  return 1.0f - 2.0f * __builtin_amdgcn_rcpf(1.0f + __expf(2.0f * x));
}
__device__ __forceinline__ ushort_t f16_bits(float f) {
  const _Float16 h = (_Float16)f;
  return __builtin_bit_cast(unsigned short, h);
}
__device__ __forceinline__ void split_f16(float f, ushort_t* hi, ushort_t* lo) {
  const _Float16 h = (_Float16)f;
  *hi = __builtin_bit_cast(unsigned short, h);
  const _Float16 l = (_Float16)(f - (float)h);
  *lo = __builtin_bit_cast(unsigned short, l);
}
// barrier that waits only on LDS ops (global stores stay in flight)
__device__ __forceinline__ void bar_lds() {
  asm volatile("s_waitcnt lgkmcnt(0)\n\ts_barrier" ::: "memory");
}

// ---------------- prep: split weights into fp16 hi/lo ----------------
__global__ __launch_bounds__(256) void prep_weights(
    const float* __restrict__ Whh0, const float* __restrict__ Whh1,
    const float* __restrict__ Wih0, const float* __restrict__ Wih1,
    ushort_t* __restrict__ w0h, ushort_t* __restrict__ w0l,
    ushort_t* __restrict__ w1h, ushort_t* __restrict__ w1l,
    ushort_t* __restrict__ wxh, ushort_t* __restrict__ wxl,
    ushort_t* __restrict__ wi1h, ushort_t* __restrict__ wi1l)
{
  const int idx = blockIdx.x * 256 + threadIdx.x;
  if (idx < 512 * HDIM) {
    split_f16(Whh0[idx], &w0h[idx], &w0l[idx]);
    split_f16(Whh1[idx], &w1h[idx], &w1l[idx]);
    split_f16(Wih1[idx], &wi1h[idx], &wi1l[idx]);
  }
  if (idx < 512 * 32) {  // Wih0 zero-padded K=16 -> 32
    const int g = idx >> 5, k = idx & 31;
    const float f = (k < IN_DIM) ? Wih0[g * IN_DIM + k] : 0.0f;
    split_f16(f, &wxh[idx], &wxl[idx]);
  }
}

#define GXS 516   // padded LDS row stride (floats) for gate-input buffers

struct L0LDS {
  __align__(16) ushort_t hfA[4][144];
  __align__(16) ushort_t hfB[4][144];
  __align__(16) ushort_t xlds[4][TC][32];
  __align__(16) float gx0s[8 * 4 * 128 * 4];  // [t_local][b][j][gate], 64 KB
};
struct L1LDS {
  __align__(16) ushort_t hfA[4][144];
  __align__(16) ushort_t hfB[4][144];
  __align__(16) float gxs[16 * GXS];          // 4 steps x 4 batches, 33 KB
  __align__(16) float wfl[HDIM];
};

// ---------------- pipelined launch: l0(ch) on WGs [0,128), gemm+l1(ch-1) on
// WGs [128,256). R16 structure (best measured operating point): 4 batches/WG,
// gate cols permuted (g = i*128 + wv*16 + row), A rows carry batch = row>>2
// -> in-lane update on all 64 lanes. Recurrent/gx1 weights fp16-hi only
// (validated R14-R16); x-path hi+lo. NEW vs R16 (L1 only): gx1 GEMM runs in
// 4-step sub-chunks into LDS (no global round-trip, no vmcnt-drain stall;
// N in half-tiles keeps Gh to 32 live VGPRs), and h2 stages to global h2buf
// with the FC pass at chunk end (validated R18/R19).
__global__ __launch_bounds__(512, 2) void lstm_pipe(
    const float* __restrict__ x,
    const ushort_t* __restrict__ w0h,
    const ushort_t* __restrict__ wxh, const ushort_t* __restrict__ wxl,
    const float* __restrict__ bih0, const float* __restrict__ bhh0,
    const ushort_t* __restrict__ wi1h,
    const ushort_t* __restrict__ w1h,
    const float* __restrict__ bih1, const float* __restrict__ bhh1,
    const float* __restrict__ Wfc, const float* __restrict__ bfc,
    float* __restrict__ out,
    float* __restrict__ h1s, float* __restrict__ c1s,
    float* __restrict__ h2s, float* __restrict__ c2s,
    ushort_t* __restrict__ h1buf,   // [2][NWGH][TC*4][HDIM] fp16
    ushort_t* __restrict__ h2buf,   // [NWGH][TC*4][HDIM] fp16
    int ch)
{
  const int tid  = threadIdx.x;
  const int lane = tid & 63;
  const int wv   = tid >> 6;
  const int row  = lane & 15;
  const int kq   = lane >> 4;    // = this lane's batch in the update phase
  const int bq   = row >> 2;     // A-fragment batch for this lane's A row
  const int j    = wv * 16 + row;

  constexpr size_t POOL =
      sizeof(L0LDS) > sizeof(L1LDS) ? sizeof(L0LDS) : sizeof(L1LDS);
  __shared__ __align__(16) char pool[POOL];

  if (blockIdx.x < NWGH) {
    // ================= L0 ROLE: chunk ch (identical to R16) ===============
    if (ch >= NCHUNK) return;
    L0LDS& S = *(L0LDS*)pool;
    const int w  = blockIdx.x;
    const int b0 = w * 4;

    f16x8 Bh[4][4];
#pragma unroll
    for (int i = 0; i < 4; ++i) {
      const int g = i * 128 + j;
#pragma unroll
      for (int kt = 0; kt < 4; ++kt)
        Bh[i][kt] = *(const f16x8*)&w0h[g * HDIM + kt * 32 + kq * 8];
    }

    // stage this chunk's x as fp16 (2 threads per (b,ts) row)
    {
      const int r = tid >> 1, half = tid & 1;
      const int b = r >> 6, ts = r & (TC - 1);
      const float* src =
          &x[((size_t)(b0 + b) * T_SEQ + ch * TC + ts) * IN_DIM + half * 8];
      const float4 v0 = *(const float4*)&src[0];
      const float4 v1 = *(const float4*)&src[4];
      ushort_t* dst = &S.xlds[b][ts][half * 8];
      dst[0] = f16_bits(v0.x); dst[1] = f16_bits(v0.y);
      dst[2] = f16_bits(v0.z); dst[3] = f16_bits(v0.w);
      dst[4] = f16_bits(v1.x); dst[5] = f16_bits(v1.y);
      dst[6] = f16_bits(v1.z); dst[7] = f16_bits(v1.w);
      *(float4*)&S.xlds[b][ts][16 + half * 8] = (float4){0.f, 0.f, 0.f, 0.f};
    }

    float bz[4];
#pragma unroll
    for (int i = 0; i < 4; ++i) bz[i] = bih0[i * 128 + j] + bhh0[i * 128 + j];
    float hc = h1s[(size_t)(b0 + kq) * HDIM + j];
    float cc = c1s[(size_t)(b0 + kq) * HDIM + j];
    S.hfA[kq][j] = f16_bits(hc);
    __syncthreads();

    ushort_t* hbp = h1buf + ((size_t)(ch & 1) * NWGH + w) * (TC * 4 * HDIM) +
                    (size_t)kq * HDIM + j;

#define L0_STEP(HIN, HOUT, TT)                                              \
  {                                                                         \
    const float4 zcu =                                                      \
        *(const float4*)&S.gx0s[((((TT) & 7) * 4 + kq) * 128 + j) * 4];     \
    f32x4 aH[4];                                                            \
    _Pragma("unroll") for (int i = 0; i < 4; ++i)                           \
        aH[i] = (f32x4){0.f, 0.f, 0.f, 0.f};                                \
    _Pragma("unroll") for (int kt = 0; kt < 4; ++kt) {                      \
      const f16x8 ah = *(const f16x8*)&HIN[bq][kt * 32 + kq * 8];           \
      _Pragma("unroll") for (int i = 0; i < 4; ++i)                         \
          aH[i] = MFMA16(ah, Bh[i][kt], aH[i]);                             \
    }                                                                       \
    const float ig = sigf(aH[0][0] + zcu.x);                                \
    const float fg = sigf(aH[1][0] + zcu.y);                                \
    const float gg = tanhf_fast(aH[2][0] + zcu.z);                          \
    const float og = sigf(aH[3][0] + zcu.w);                                \
    cc = fg * cc + ig * gg;                                                 \
    hc = og * tanhf_fast(cc);                                               \
    const ushort_t hbits = f16_bits(hc);                                    \
    HOUT[kq][j] = hbits;                                                    \
    *hbp = hbits;                                                           \
    hbp += 4 * HDIM;                                                        \
    bar_lds();                                                              \
  }

    for (int sc = 0; sc < TC / 8; ++sc) {
      // ---- sub-chunk x-GEMM: gx0 = x . Wih0^T + bias (hi+lo) -> LDS ----
      {
        f16x8 Bxh[4], Bxl[4];
#pragma unroll
        for (int i = 0; i < 4; ++i) {
          const int g = i * 128 + j;
          Bxh[i] = *(const f16x8*)&wxh[g * 32 + kq * 8];
          Bxl[i] = *(const f16x8*)&wxl[g * 32 + kq * 8];
        }
#pragma unroll
        for (int mt = 0; mt < 2; ++mt) {
          const f16x8 a = *(const f16x8*)
              &S.xlds[row & 3][sc * 8 + mt * 4 + (row >> 2)][kq * 8];
          f32x4 acc[4];
#pragma unroll
          for (int i = 0; i < 4; ++i) acc[i] = (f32x4){0.f, 0.f, 0.f, 0.f};
#pragma unroll
          for (int i = 0; i < 4; ++i) acc[i] = MFMA16(a, Bxh[i], acc[i]);
#pragma unroll
          for (int i = 0; i < 4; ++i) acc[i] = MFMA16(a, Bxl[i], acc[i]);
#pragma unroll
          for (int r = 0; r < 4; ++r) {
            float4 o;
            o.x = acc[0][r] + bz[0];
            o.y = acc[1][r] + bz[1];
            o.z = acc[2][r] + bz[2];
            o.w = acc[3][r] + bz[3];
            *(float4*)&S.gx0s[(((mt * 4 + kq) * 4 + r) * 128 + j) * 4] = o;
          }
        }
      }
      __syncthreads();
#pragma unroll 1
      for (int q = 0; q < 4; ++q) {
        const int tt = sc * 8 + q * 2;
        L0_STEP(S.hfA, S.hfB, tt);
        L0_STEP(S.hfB, S.hfA, tt + 1);
      }
    }
#undef L0_STEP

    h1s[(size_t)(b0 + kq) * HDIM + j] = hc;
    c1s[(size_t)(b0 + kq) * HDIM + j] = cc;
  } else {
    // ================= L1 ROLE: gemm(LDS) + recurrence, FC at end =========
    if (ch == 0) return;
    L1LDS& S = *(L1LDS*)pool;
    const int w  = blockIdx.x - NWGH;
    const int b0 = w * 4;

    const ushort_t* hb =
        h1buf + ((size_t)((ch - 1) & 1) * NWGH + w) * (TC * 4 * HDIM);
    ushort_t* h2p = h2buf + (size_t)w * (TC * 4 * HDIM) +
                    (size_t)kq * HDIM + j;

    if (tid < HDIM) S.wfl[tid] = Wfc[tid];

    float bz1[4];
#pragma unroll
    for (int i = 0; i < 4; ++i) bz1[i] = bih1[i * 128 + j] + bhh1[i * 128 + j];
    f16x8 Rh[4][4];
#pragma unroll
    for (int i = 0; i < 4; ++i) {
      const int g = i * 128 + j;
#pragma unroll
      for (int kt = 0; kt < 4; ++kt)
        Rh[i][kt] = *(const f16x8*)&w1h[g * HDIM + kt * 32 + kq * 8];
    }

    float hc = h2s[(size_t)(b0 + kq) * HDIM + j];
    float cc = c2s[(size_t)(b0 + kq) * HDIM + j];
    S.hfA[kq][j] = f16_bits(hc);
    __syncthreads();

#define L1_STEP(HIN, HOUT, TT)                                              \
  {                                                                         \
    const float4 zcu =                                                      \
        *(const float4*)&S.gxs[((((TT) & 3) * 4 + kq)) * GXS + j * 4];      \
    f32x4 aH[4];                                                            \
    _Pragma("unroll") for (int i = 0; i < 4; ++i)                           \
        aH[i] = (f32x4){0.f, 0.f, 0.f, 0.f};                                \
    _Pragma("unroll") for (int kt = 0; kt < 4; ++kt) {                      \
      const f16x8 ah = *(const f16x8*)&HIN[bq][kt * 32 + kq * 8];           \
      _Pragma("unroll") for (int i = 0; i < 4; ++i)                         \
          aH[i] = MFMA16(ah, Rh[i][kt], aH[i]);                             \
    }                                                                       \
    const float ig = sigf(aH[0][0] + zcu.x);                                \
    const float fg = sigf(aH[1][0] + zcu.y);                                \
    const float gg = tanhf_fast(aH[2][0] + zcu.z);                          \
    const float og = sigf(aH[3][0] + zcu.w);                                \
    cc = fg * cc + ig * gg;                                                 \
    hc = og * tanhf_fast(cc);                                               \
    const ushort_t hbits = f16_bits(hc);                                    \
    HOUT[kq][j] = hbits;                                                    \
    h2p[0] = hbits;                                                         \
    h2p += 4 * HDIM;                                                        \
    bar_lds();                                                              \
  }

    for (int sc = 0; sc < TC / 4; ++sc) {
      // ---- sub-chunk gx1 GEMM (hi only) -> LDS, N in half-tiles ----
      // M-tile rows sc*16+m, m = t_local*4 + b; C row m = kq*4+r ->
      // (t_local = kq, batch = r) -> gxs row m.
#pragma unroll
      for (int half = 0; half < 2; ++half) {
        f16x8 Gh[2][4];
#pragma unroll
        for (int i2 = 0; i2 < 2; ++i2) {
          const int g = (half * 2 + i2) * 128 + j;
#pragma unroll
          for (int kt = 0; kt < 4; ++kt)
            Gh[i2][kt] = *(const f16x8*)&wi1h[g * HDIM + kt * 32 + kq * 8];
        }
        f32x4 acc[2];
        acc[0] = (f32x4){0.f, 0.f, 0.f, 0.f};
        acc[1] = (f32x4){0.f, 0.f, 0.f, 0.f};
#pragma unroll
        for (int kt = 0; kt < 4; ++kt) {
          const f16x8 a =
              *(const f16x8*)&hb[(size_t)(sc * 16 + row) * HDIM + kt * 32 + kq * 8];
          acc[0] = MFMA16(a, Gh[0][kt], acc[0]);
          acc[1] = MFMA16(a, Gh[1][kt], acc[1]);
        }
#pragma unroll
        for (int r = 0; r < 4; ++r) {
          float2 o;
          o.x = acc[0][r] + bz1[half * 2];
          o.y = acc[1][r] + bz1[half * 2 + 1];
          *(float2*)&S.gxs[(kq * 4 + r) * GXS + j * 4 + half * 2] = o;
        }
      }
      bar_lds();
      const int t0s = sc * 4;
      L1_STEP(S.hfA, S.hfB, t0s);
      L1_STEP(S.hfB, S.hfA, t0s + 1);
      L1_STEP(S.hfA, S.hfB, t0s + 2);
      L1_STEP(S.hfB, S.hfA, t0s + 3);
    }
#undef L1_STEP

    h2s[(size_t)(b0 + kq) * HDIM + j] = hc;
    c2s[(size_t)(b0 + kq) * HDIM + j] = cc;
    __syncthreads();  // drain h2buf stores before FC reads

    // ---- FC pass over the chunk (latency-tolerant, once per chunk) ----
    if (tid < TC * 4) {
      const int tt = tid >> 2, b = tid & 3;
      const ushort_t* hrow =
          h2buf + (size_t)w * (TC * 4 * HDIM) + (size_t)tid * HDIM;
      const float bfcv = bfc[0];
      float s0 = 0.f, s1 = 0.f, s2 = 0.f, s3 = 0.f;
#pragma unroll
      for (int q = 0; q < HDIM / 8; ++q) {
        const f16x8 hv = *(const f16x8*)&hrow[q * 8];
        const float* wq = &S.wfl[q * 8];
        s0 += fmaxf((float)hv[0], 0.f) * wq[0];
        s1 += fmaxf((float)hv[1], 0.f) * wq[1];
        s2 += fmaxf((float)hv[2], 0.f) * wq[2];
        s3 += fmaxf((float)hv[3], 0.f) * wq[3];
        s0 += fmaxf((float)hv[4], 0.f) * wq[4];
        s1 += fmaxf((float)hv[5], 0.f) * wq[5];
        s2 += fmaxf((float)hv[6], 0.f) * wq[6];
        s3 += fmaxf((float)hv[7], 0.f) * wq[7];
      }
      const float s = s0 + s1 + s2 + s3 + bfcv;
      out[(size_t)(b0 + b) * T_SEQ + (ch - 1) * TC + tt] = fmaxf(s, 0.0f);
    }
  }
}

extern "C" void kernel_launch(void* const* d_in, const int* in_sizes, int n_in,
                              void* d_out, int out_size, void* d_ws, size_t ws_size,
                              hipStream_t stream)
{
  const float* x    = (const float*)d_in[0];
  const float* Wih0 = (const float*)d_in[1];
  const float* Whh0 = (const float*)d_in[2];
  const float* bih0 = (const float*)d_in[3];
  const float* bhh0 = (const float*)d_in[4];
  const float* Wih1 = (const float*)d_in[5];
  const float* Whh1 = (const float*)d_in[6];
  const float* bih1 = (const float*)d_in[7];
  const float* bhh1 = (const float*)d_in[8];
  const float* Wfc  = (const float*)d_in[9];
  const float* bfc  = (const float*)d_in[10];
  float* out = (float*)d_out;

  const size_t stateN = (size_t)NBATCH * HDIM;  // 65536
  float* h1s = (float*)d_ws;
  float* c1s = h1s + stateN;
  float* h2s = c1s + stateN;
  float* c2s = h2s + stateN;
  ushort_t* w0h  = (ushort_t*)(c2s + stateN);
  ushort_t* w0l  = w0h  + stateN;
  ushort_t* w1h  = w0l  + stateN;
  ushort_t* w1l  = w1h  + stateN;
  ushort_t* wi1h = w1l  + stateN;
  ushort_t* wi1l = wi1h + stateN;
  ushort_t* wxh  = wi1l + stateN;
  ushort_t* wxl  = wxh  + 512 * 32;
  ushort_t* h1buf = wxl + 512 * 32;   // 2*NWGH*TC*4*HDIM fp16 = 16.8 MB
  ushort_t* h2buf = h1buf + (size_t)2 * NWGH * TC * 4 * HDIM;  // 8.4 MB

  // zero-init recurrent states (h0 = c0 = 0)
  (void)hipMemsetAsync(d_ws, 0, 4 * stateN * sizeof(float), stream);
  hipLaunchKernelGGL(prep_weights, dim3(256), dim3(256), 0, stream,
                     Whh0, Whh1, Wih0, Wih1,
                     w0h, w0l, w1h, w1l, wxh, wxl, wi1h, wi1l);

  for (int ch = 0; ch <= NCHUNK; ++ch) {
    hipLaunchKernelGGL(lstm_pipe, dim3(2 * NWGH), dim3(512), 0, stream,
                       x, w0h, wxh, wxl, bih0, bhh0,
                       wi1h, w1h, bih1, bhh1, Wfc, bfc,
                       out, h1s, c1s, h2s, c2s, h1buf, h2buf, ch);
  }
}

// Round 22
// 940.669 us; speedup vs baseline: 2.4163x; 1.0194x over previous
//
#include <hip/hip_runtime.h>

#define T_SEQ  1024
#define NBATCH 512
#define IN_DIM 16
#define HDIM   128
#define G4     (4 * HDIM)
#define TC     64
#define NCHUNK (T_SEQ / TC)
#define NWGH   128   // WGs per role; 4 batches per WG

typedef unsigned short ushort_t;
typedef __attribute__((ext_vector_type(8))) _Float16 f16x8;
typedef __attribute__((ext_vector_type(4))) float f32x4;

#define MFMA16(a, b, c) __builtin_amdgcn_mfma_f32_16x16x32_f16((a), (b), (c), 0, 0, 0)

__device__ __forceinline__ float sigf(float x) {
  return __builtin_amdgcn_rcpf(1.0f + __expf(-x));
}
__device__ __forceinline__ float tanhf_fast(float x) {
  return 1.0f - 2.0f * __builtin_amdgcn_rcpf(1.0f + __expf(2.0f * x));
}
__device__ __forceinline__ ushort_t f16_bits(float f) {
  const _Float16 h = (_Float16)f;
  return __builtin_bit_cast(unsigned short, h);
}
__device__ __forceinline__ void split_f16(float f, ushort_t* hi, ushort_t* lo) {
  const _Float16 h = (_Float16)f;
  *hi = __builtin_bit_cast(unsigned short, h);
  const _Float16 l = (_Float16)(f - (float)h);
  *lo = __builtin_bit_cast(unsigned short, l);
}
// barrier that waits only on LDS ops (global stores stay in flight)
__device__ __forceinline__ void bar_lds() {
  asm volatile("s_waitcnt lgkmcnt(0)\n\ts_barrier" ::: "memory");
}

// ---------------- prep: split weights into fp16 hi/lo ----------------
__global__ __launch_bounds__(256) void prep_weights(
    const float* __restrict__ Whh0, const float* __restrict__ Whh1,
    const float* __restrict__ Wih0, const float* __restrict__ Wih1,
    ushort_t* __restrict__ w0h, ushort_t* __restrict__ w0l,
    ushort_t* __restrict__ w1h, ushort_t* __restrict__ w1l,
    ushort_t* __restrict__ wxh, ushort_t* __restrict__ wxl,
    ushort_t* __restrict__ wi1h, ushort_t* __restrict__ wi1l)
{
  const int idx = blockIdx.x * 256 + threadIdx.x;
  if (idx < 512 * HDIM) {
    split_f16(Whh0[idx], &w0h[idx], &w0l[idx]);
    split_f16(Whh1[idx], &w1h[idx], &w1l[idx]);
    split_f16(Wih1[idx], &wi1h[idx], &wi1l[idx]);
  }
  if (idx < 512 * 32) {  // Wih0 zero-padded K=16 -> 32
    const int g = idx >> 5, k = idx & 31;
    const float f = (k < IN_DIM) ? Wih0[g * IN_DIM + k] : 0.0f;
    split_f16(f, &wxh[idx], &wxl[idx]);
  }
}

// LDS overlay (union of the two roles' pools)
struct L0LDS {
  __align__(16) ushort_t hfA[4][144];
  __align__(16) ushort_t hfB[4][144];
  __align__(16) ushort_t xlds[4][TC][32];
  __align__(16) float gx0s[8 * 4 * 128 * 4];  // [t_local][b][j][gate], 64 KB
};
struct L1LDS {
  __align__(16) ushort_t hfA[4][144];
  __align__(16) ushort_t hfB[4][144];
  __align__(16) ushort_t h2l[TC][4][136];
  __align__(16) float wfl[HDIM];
};

// ---------------- pipelined launch: l0(ch) on WGs [0,128), gemm+l1(ch-1) on
// WGs [128,256). R16 structure (best measured operating point). Gate cols
// permuted (g = i*128 + wv*16 + row); A rows carry batch = row>>2 -> in-lane
// update on all 64 lanes. Recurrent/gx1 weights fp16-hi only (validated
// R14-R16); x-path hi+lo hoisted into per-8-step sub-chunk GEMMs. NEW vs the
// 927us kernel: the 4-deep recurrent MFMA chain is split into two 2-deep
// independent chains (aHa: kt 0-1, aHb: kt 2-3; gates read element [0] only)
// to cut ~80 cyc off every step's serial path. +16 VGPR, no spill.
__global__ __launch_bounds__(512, 2) void lstm_pipe(
    const float* __restrict__ x,
    const ushort_t* __restrict__ w0h,
    const ushort_t* __restrict__ wxh, const ushort_t* __restrict__ wxl,
    const float* __restrict__ bih0, const float* __restrict__ bhh0,
    const ushort_t* __restrict__ wi1h,
    const ushort_t* __restrict__ w1h,
    const float* __restrict__ bih1, const float* __restrict__ bhh1,
    const float* __restrict__ Wfc, const float* __restrict__ bfc,
    float* __restrict__ out,
    float* __restrict__ h1s, float* __restrict__ c1s,
    float* __restrict__ h2s, float* __restrict__ c2s,
    ushort_t* __restrict__ h1buf,   // [2][NWGH][TC*4][HDIM] fp16
    float* __restrict__ gx1buf,     // [NWGH][TC*4][HDIM][4]
    int ch)
{
  const int tid  = threadIdx.x;
  const int lane = tid & 63;
  const int wv   = tid >> 6;
  const int row  = lane & 15;
  const int kq   = lane >> 4;    // = this lane's batch in the update phase
  const int bq   = row >> 2;     // A-fragment batch for this lane's A row
  const int j    = wv * 16 + row;

  constexpr size_t POOL =
      sizeof(L0LDS) > sizeof(L1LDS) ? sizeof(L0LDS) : sizeof(L1LDS);
  __shared__ __align__(16) char pool[POOL];

  if (blockIdx.x < NWGH) {
    // ================= L0 ROLE: chunk ch =================
    if (ch >= NCHUNK) return;
    L0LDS& S = *(L0LDS*)pool;
    const int w  = blockIdx.x;
    const int b0 = w * 4;

    f16x8 Bh[4][4];
#pragma unroll
    for (int i = 0; i < 4; ++i) {
      const int g = i * 128 + j;
#pragma unroll
      for (int kt = 0; kt < 4; ++kt)
        Bh[i][kt] = *(const f16x8*)&w0h[g * HDIM + kt * 32 + kq * 8];
    }

    // stage this chunk's x as fp16 (2 threads per (b,ts) row)
    {
      const int r = tid >> 1, half = tid & 1;
      const int b = r >> 6, ts = r & (TC - 1);
      const float* src =
          &x[((size_t)(b0 + b) * T_SEQ + ch * TC + ts) * IN_DIM + half * 8];
      const float4 v0 = *(const float4*)&src[0];
      const float4 v1 = *(const float4*)&src[4];
      ushort_t* dst = &S.xlds[b][ts][half * 8];
      dst[0] = f16_bits(v0.x); dst[1] = f16_bits(v0.y);
      dst[2] = f16_bits(v0.z); dst[3] = f16_bits(v0.w);
      dst[4] = f16_bits(v1.x); dst[5] = f16_bits(v1.y);
      dst[6] = f16_bits(v1.z); dst[7] = f16_bits(v1.w);
      *(float4*)&S.xlds[b][ts][16 + half * 8] = (float4){0.f, 0.f, 0.f, 0.f};
    }

    float bz[4];
#pragma unroll
    for (int i = 0; i < 4; ++i) bz[i] = bih0[i * 128 + j] + bhh0[i * 128 + j];
    float hc = h1s[(size_t)(b0 + kq) * HDIM + j];
    float cc = c1s[(size_t)(b0 + kq) * HDIM + j];
    S.hfA[kq][j] = f16_bits(hc);
    __syncthreads();

    ushort_t* hbp = h1buf + ((size_t)(ch & 1) * NWGH + w) * (TC * 4 * HDIM) +
                    (size_t)kq * HDIM + j;

#define L0_STEP(HIN, HOUT, TT)                                              \
  {                                                                         \
    const float4 zcu =                                                      \
        *(const float4*)&S.gx0s[((((TT) & 7) * 4 + kq) * 128 + j) * 4];     \
    f32x4 aHa[4], aHb[4];                                                   \
    _Pragma("unroll") for (int i = 0; i < 4; ++i) {                         \
      aHa[i] = (f32x4){0.f, 0.f, 0.f, 0.f};                                 \
      aHb[i] = (f32x4){0.f, 0.f, 0.f, 0.f};                                 \
    }                                                                       \
    {                                                                       \
      const f16x8 ah0 = *(const f16x8*)&HIN[bq][0 * 32 + kq * 8];           \
      const f16x8 ah1 = *(const f16x8*)&HIN[bq][1 * 32 + kq * 8];           \
      const f16x8 ah2 = *(const f16x8*)&HIN[bq][2 * 32 + kq * 8];           \
      const f16x8 ah3 = *(const f16x8*)&HIN[bq][3 * 32 + kq * 8];           \
      _Pragma("unroll") for (int i = 0; i < 4; ++i)                         \
          aHa[i] = MFMA16(ah0, Bh[i][0], aHa[i]);                           \
      _Pragma("unroll") for (int i = 0; i < 4; ++i)                         \
          aHb[i] = MFMA16(ah2, Bh[i][2], aHb[i]);                           \
      _Pragma("unroll") for (int i = 0; i < 4; ++i)                         \
          aHa[i] = MFMA16(ah1, Bh[i][1], aHa[i]);                           \
      _Pragma("unroll") for (int i = 0; i < 4; ++i)                         \
          aHb[i] = MFMA16(ah3, Bh[i][3], aHb[i]);                           \
    }                                                                       \
    const float ig = sigf(aHa[0][0] + aHb[0][0] + zcu.x);                   \
    const float fg = sigf(aHa[1][0] + aHb[1][0] + zcu.y);                   \
    const float gg = tanhf_fast(aHa[2][0] + aHb[2][0] + zcu.z);             \
    const float og = sigf(aHa[3][0] + aHb[3][0] + zcu.w);                   \
    cc = fg * cc + ig * gg;                                                 \
    hc = og * tanhf_fast(cc);                                               \
    const ushort_t hbits = f16_bits(hc);                                    \
    HOUT[kq][j] = hbits;                                                    \
    *hbp = hbits;                                                           \
    hbp += 4 * HDIM;                                                        \
    bar_lds();                                                              \
  }

    for (int sc = 0; sc < TC / 8; ++sc) {
      // ---- sub-chunk x-GEMM: gx0 = x . Wih0^T + bias (hi+lo) -> LDS ----
      {
        f16x8 Bxh[4], Bxl[4];
#pragma unroll
        for (int i = 0; i < 4; ++i) {
          const int g = i * 128 + j;
          Bxh[i] = *(const f16x8*)&wxh[g * 32 + kq * 8];
          Bxl[i] = *(const f16x8*)&wxl[g * 32 + kq * 8];
        }
#pragma unroll
        for (int mt = 0; mt < 2; ++mt) {
          const f16x8 a = *(const f16x8*)
              &S.xlds[row & 3][sc * 8 + mt * 4 + (row >> 2)][kq * 8];
          f32x4 acc[4];
#pragma unroll
          for (int i = 0; i < 4; ++i) acc[i] = (f32x4){0.f, 0.f, 0.f, 0.f};
#pragma unroll
          for (int i = 0; i < 4; ++i) acc[i] = MFMA16(a, Bxh[i], acc[i]);
#pragma unroll
          for (int i = 0; i < 4; ++i) acc[i] = MFMA16(a, Bxl[i], acc[i]);
#pragma unroll
          for (int r = 0; r < 4; ++r) {
            float4 o;
            o.x = acc[0][r] + bz[0];
            o.y = acc[1][r] + bz[1];
            o.z = acc[2][r] + bz[2];
            o.w = acc[3][r] + bz[3];
            *(float4*)&S.gx0s[(((mt * 4 + kq) * 4 + r) * 128 + j) * 4] = o;
          }
        }
      }
      __syncthreads();
#pragma unroll 1
      for (int q = 0; q < 4; ++q) {
        const int tt = sc * 8 + q * 2;
        L0_STEP(S.hfA, S.hfB, tt);
        L0_STEP(S.hfB, S.hfA, tt + 1);
      }
    }
#undef L0_STEP

    h1s[(size_t)(b0 + kq) * HDIM + j] = hc;
    c1s[(size_t)(b0 + kq) * HDIM + j] = cc;
  } else {
    // ================= L1 ROLE: gemm + recurrence, FC at chunk end =========
    if (ch == 0) return;
    L1LDS& S = *(L1LDS*)pool;
    const int w  = blockIdx.x - NWGH;
    const int b0 = w * 4;

    const ushort_t* hb =
        h1buf + ((size_t)((ch - 1) & 1) * NWGH + w) * (TC * 4 * HDIM);
    float* gx = gx1buf + (size_t)w * (TC * 4 * HDIM * 4);

    if (tid < HDIM) S.wfl[tid] = Wfc[tid];

    // ---- gemm: gx1 = h1 . Wih1^T + biases (hi only), own 4 batches ----
    {
      f16x8 Gh[4][4];
      float bz1[4];
#pragma unroll
      for (int i = 0; i < 4; ++i) {
        const int g = i * 128 + j;
#pragma unroll
        for (int kt = 0; kt < 4; ++kt)
          Gh[i][kt] = *(const f16x8*)&wi1h[g * HDIM + kt * 32 + kq * 8];
        bz1[i] = bih1[i * 128 + j] + bhh1[i * 128 + j];
      }
#pragma unroll 2
      for (int mt = 0; mt < TC * 4 / 16; ++mt) {
        f32x4 acc[4];
#pragma unroll
        for (int i = 0; i < 4; ++i) acc[i] = (f32x4){0.f, 0.f, 0.f, 0.f};
#pragma unroll
        for (int kt = 0; kt < 4; ++kt) {
          const f16x8 a =
              *(const f16x8*)&hb[(size_t)(mt * 16 + row) * HDIM + kt * 32 + kq * 8];
#pragma unroll
          for (int i = 0; i < 4; ++i) acc[i] = MFMA16(a, Gh[i][kt], acc[i]);
        }
#pragma unroll
        for (int r = 0; r < 4; ++r) {
          const int m = mt * 16 + kq * 4 + r;
          float4 o;
          o.x = acc[0][r] + bz1[0];
          o.y = acc[1][r] + bz1[1];
          o.z = acc[2][r] + bz1[2];
          o.w = acc[3][r] + bz1[3];
          *(float4*)&gx[((size_t)m * HDIM + j) * 4] = o;
        }
      }
    }

    float hc = h2s[(size_t)(b0 + kq) * HDIM + j];
    float cc = c2s[(size_t)(b0 + kq) * HDIM + j];
    S.hfA[kq][j] = f16_bits(hc);
    __syncthreads();  // drains gemm stores (vmcnt) + hfA/wfl staging

    f16x8 Rh[4][4];
#pragma unroll
    for (int i = 0; i < 4; ++i) {
      const int g = i * 128 + j;
#pragma unroll
      for (int kt = 0; kt < 4; ++kt)
        Rh[i][kt] = *(const f16x8*)&w1h[g * HDIM + kt * 32 + kq * 8];
    }

    // per-step stride: 4 rows x HDIM x 4 floats = 2048 floats = 512 float4
    const float4* gxp = (const float4*)&gx[((size_t)kq * HDIM + j) * 4];
    float4 zcc = *gxp;
    gxp += 512;

#define L1_STEP(HIN, HOUT, TT)                                              \
  {                                                                         \
    const float4 zcu = zcc;                                                 \
    if ((TT) + 1 < TC) { zcc = *gxp; gxp += 512; }                          \
    f32x4 aHa[4], aHb[4];                                                   \
    _Pragma("unroll") for (int i = 0; i < 4; ++i) {                         \
      aHa[i] = (f32x4){0.f, 0.f, 0.f, 0.f};                                 \
      aHb[i] = (f32x4){0.f, 0.f, 0.f, 0.f};                                 \
    }                                                                       \
    {                                                                       \
      const f16x8 ah0 = *(const f16x8*)&HIN[bq][0 * 32 + kq * 8];           \
      const f16x8 ah1 = *(const f16x8*)&HIN[bq][1 * 32 + kq * 8];           \
      const f16x8 ah2 = *(const f16x8*)&HIN[bq][2 * 32 + kq * 8];           \
      const f16x8 ah3 = *(const f16x8*)&HIN[bq][3 * 32 + kq * 8];           \
      _Pragma("unroll") for (int i = 0; i < 4; ++i)                         \
          aHa[i] = MFMA16(ah0, Rh[i][0], aHa[i]);                           \
      _Pragma("unroll") for (int i = 0; i < 4; ++i)                         \
          aHb[i] = MFMA16(ah2, Rh[i][2], aHb[i]);                           \
      _Pragma("unroll") for (int i = 0; i < 4; ++i)                         \
          aHa[i] = MFMA16(ah1, Rh[i][1], aHa[i]);                           \
      _Pragma("unroll") for (int i = 0; i < 4; ++i)                         \
          aHb[i] = MFMA16(ah3, Rh[i][3], aHb[i]);                           \
    }                                                                       \
    const float ig = sigf(aHa[0][0] + aHb[0][0] + zcu.x);                   \
    const float fg = sigf(aHa[1][0] + aHb[1][0] + zcu.y);                   \
    const float gg = tanhf_fast(aHa[2][0] + aHb[2][0] + zcu.z);             \
    const float og = sigf(aHa[3][0] + aHb[3][0] + zcu.w);                   \
    cc = fg * cc + ig * gg;                                                 \
    hc = og * tanhf_fast(cc);                                               \
    const ushort_t hbits = f16_bits(hc);                                    \
    HOUT[kq][j] = hbits;                                                    \
    S.h2l[TT][kq][j] = hbits;                                               \
    bar_lds();                                                              \
  }

    for (int tt = 0; tt < TC; tt += 2) {
      L1_STEP(S.hfA, S.hfB, tt);
      L1_STEP(S.hfB, S.hfA, tt + 1);
    }
#undef L1_STEP

    h2s[(size_t)(b0 + kq) * HDIM + j] = hc;
    c2s[(size_t)(b0 + kq) * HDIM + j] = cc;

    // ---- FC pass over the chunk (latency-tolerant, once per chunk) ----
    // last bar_lds made all h2l writes visible
    if (tid < TC * 4) {
      const int tt = tid >> 2, b = tid & 3;
      const float bfcv = bfc[0];
      float s0 = 0.f, s1 = 0.f, s2 = 0.f, s3 = 0.f;
#pragma unroll
      for (int q = 0; q < HDIM / 8; ++q) {
        const f16x8 hv = *(const f16x8*)&S.h2l[tt][b][q * 8];
        const float* wq = &S.wfl[q * 8];
        s0 += fmaxf((float)hv[0], 0.f) * wq[0];
        s1 += fmaxf((float)hv[1], 0.f) * wq[1];
        s2 += fmaxf((float)hv[2], 0.f) * wq[2];
        s3 += fmaxf((float)hv[3], 0.f) * wq[3];
        s0 += fmaxf((float)hv[4], 0.f) * wq[4];
        s1 += fmaxf((float)hv[5], 0.f) * wq[5];
        s2 += fmaxf((float)hv[6], 0.f) * wq[6];
        s3 += fmaxf((float)hv[7], 0.f) * wq[7];
      }
      const float s = s0 + s1 + s2 + s3 + bfcv;
      out[(size_t)(b0 + b) * T_SEQ + (ch - 1) * TC + tt] = fmaxf(s, 0.0f);
    }
  }
}

extern "C" void kernel_launch(void* const* d_in, const int* in_sizes, int n_in,
                              void* d_out, int out_size, void* d_ws, size_t ws_size,
                              hipStream_t stream)
{
  const float* x    = (const float*)d_in[0];
  const float* Wih0 = (const float*)d_in[1];
  const float* Whh0 = (const float*)d_in[2];
  const float* bih0 = (const float*)d_in[3];
  const float* bhh0 = (const float*)d_in[4];
  const float* Wih1 = (const float*)d_in[5];
  const float* Whh1 = (const float*)d_in[6];
  const float* bih1 = (const float*)d_in[7];
  const float* bhh1 = (const float*)d_in[8];
  const float* Wfc  = (const float*)d_in[9];
  const float* bfc  = (const float*)d_in[10];
  float* out = (float*)d_out;

  const size_t stateN = (size_t)NBATCH * HDIM;  // 65536
  float* h1s = (float*)d_ws;
  float* c1s = h1s + stateN;
  float* h2s = c1s + stateN;
  float* c2s = h2s + stateN;
  ushort_t* w0h  = (ushort_t*)(c2s + stateN);
  ushort_t* w0l  = w0h  + stateN;
  ushort_t* w1h  = w0l  + stateN;
  ushort_t* w1l  = w1h  + stateN;
  ushort_t* wi1h = w1l  + stateN;
  ushort_t* wi1l = wi1h + stateN;
  ushort_t* wxh  = wi1l + stateN;
  ushort_t* wxl  = wxh  + 512 * 32;
  ushort_t* h1buf = wxl + 512 * 32;                       // 2*NWGH*TC*4*HDIM fp16
  float* gx1buf = (float*)(h1buf + (size_t)2 * NWGH * TC * 4 * HDIM);

  // zero-init recurrent states (h0 = c0 = 0)
  (void)hipMemsetAsync(d_ws, 0, 4 * stateN * sizeof(float), stream);
  hipLaunchKernelGGL(prep_weights, dim3(256), dim3(256), 0, stream,
                     Whh0, Whh1, Wih0, Wih1,
                     w0h, w0l, w1h, w1l, wxh, wxl, wi1h, wi1l);

  for (int ch = 0; ch <= NCHUNK; ++ch) {
    hipLaunchKernelGGL(lstm_pipe, dim3(2 * NWGH), dim3(512), 0, stream,
                       x, w0h, wxh, wxl, bih0, bhh0,
                       wi1h, w1h, bih1, bhh1, Wfc, bfc,
                       out, h1s, c1s, h2s, c2s, h1buf, gx1buf, ch);
  }
}

// Round 23
// 918.645 us; speedup vs baseline: 2.4743x; 1.0240x over previous
//
#include <hip/hip_runtime.h>

#define T_SEQ  1024
#define NBATCH 512
#define IN_DIM 16
#define HDIM   128
#define G4     (4 * HDIM)
#define TC     64
#define NCHUNK (T_SEQ / TC)
#define NWGH   128   // WGs per role; 4 batches per WG

typedef unsigned short ushort_t;
typedef __attribute__((ext_vector_type(8))) _Float16 f16x8;
typedef __attribute__((ext_vector_type(4))) float f32x4;

#define MFMA16(a, b, c) __builtin_amdgcn_mfma_f32_16x16x32_f16((a), (b), (c), 0, 0, 0)

__device__ __forceinline__ float sigf(float x) {
  return __builtin_amdgcn_rcpf(1.0f + __expf(-x));
}
__device__ __forceinline__ float tanhf_fast(float x) {
  return 1.0f - 2.0f * __builtin_amdgcn_rcpf(1.0f + __expf(2.0f * x));
}
__device__ __forceinline__ ushort_t f16_bits(float f) {
  const _Float16 h = (_Float16)f;
  return __builtin_bit_cast(unsigned short, h);
}
__device__ __forceinline__ void split_f16(float f, ushort_t* hi, ushort_t* lo) {
  const _Float16 h = (_Float16)f;
  *hi = __builtin_bit_cast(unsigned short, h);
  const _Float16 l = (_Float16)(f - (float)h);
  *lo = __builtin_bit_cast(unsigned short, l);
}
// barrier that waits only on LDS ops (global stores stay in flight)
__device__ __forceinline__ void bar_lds() {
  asm volatile("s_waitcnt lgkmcnt(0)\n\ts_barrier" ::: "memory");
}

// ---------------- prep: split weights into fp16 hi/lo ----------------
__global__ __launch_bounds__(256) void prep_weights(
    const float* __restrict__ Whh0, const float* __restrict__ Whh1,
    const float* __restrict__ Wih0, const float* __restrict__ Wih1,
    ushort_t* __restrict__ w0h, ushort_t* __restrict__ w0l,
    ushort_t* __restrict__ w1h, ushort_t* __restrict__ w1l,
    ushort_t* __restrict__ wxh, ushort_t* __restrict__ wxl,
    ushort_t* __restrict__ wi1h, ushort_t* __restrict__ wi1l)
{
  const int idx = blockIdx.x * 256 + threadIdx.x;
  if (idx < 512 * HDIM) {
    split_f16(Whh0[idx], &w0h[idx], &w0l[idx]);
    split_f16(Whh1[idx], &w1h[idx], &w1l[idx]);
    split_f16(Wih1[idx], &wi1h[idx], &wi1l[idx]);
  }
  if (idx < 512 * 32) {  // Wih0 zero-padded K=16 -> 32
    const int g = idx >> 5, k = idx & 31;
    const float f = (k < IN_DIM) ? Wih0[g * IN_DIM + k] : 0.0f;
    split_f16(f, &wxh[idx], &wxl[idx]);
  }
}

// LDS overlay (union of the two roles' pools)
struct L0LDS {
  __align__(16) ushort_t hfA[4][144];
  __align__(16) ushort_t hfB[4][144];
  __align__(16) ushort_t xlds[4][TC][32];
  __align__(16) float gx0s[8 * 4 * 128 * 4];  // [t_local][b][j][gate], 64 KB
};
struct L1LDS {
  __align__(16) ushort_t hfA[4][144];
  __align__(16) ushort_t hfB[4][144];
  __align__(16) ushort_t h2l[TC][4][136];
  __align__(16) float wfl[HDIM];
};

// ---------------- pipelined launch: l0(ch) on WGs [0,128), gemm+l1(ch-1) on
// WGs [128,256). Gate cols permuted (g = i*128 + wv*16 + row); A rows carry
// batch = row>>2 -> in-lane update on all 64 lanes. Recurrent h.Whh uses fp16
// HI only (validated R14/R15). L0's x-contribution hoisted into per-8-step
// sub-chunk GEMMs (x.Wih0^T + bias -> LDS gx0s). L1's gx1 GEMM drops the
// W_lo term. Best measured configuration (R16: 926.7 us).
__global__ __launch_bounds__(512, 2) void lstm_pipe(
    const float* __restrict__ x,
    const ushort_t* __restrict__ w0h,
    const ushort_t* __restrict__ wxh, const ushort_t* __restrict__ wxl,
    const float* __restrict__ bih0, const float* __restrict__ bhh0,
    const ushort_t* __restrict__ wi1h,
    const ushort_t* __restrict__ w1h,
    const float* __restrict__ bih1, const float* __restrict__ bhh1,
    const float* __restrict__ Wfc, const float* __restrict__ bfc,
    float* __restrict__ out,
    float* __restrict__ h1s, float* __restrict__ c1s,
    float* __restrict__ h2s, float* __restrict__ c2s,
    ushort_t* __restrict__ h1buf,   // [2][NWGH][TC*4][HDIM] fp16
    float* __restrict__ gx1buf,     // [NWGH][TC*4][HDIM][4]
    int ch)
{
  const int tid  = threadIdx.x;
  const int lane = tid & 63;
  const int wv   = tid >> 6;
  const int row  = lane & 15;
  const int kq   = lane >> 4;    // = this lane's batch in the update phase
  const int bq   = row >> 2;     // A-fragment batch for this lane's A row
  const int j    = wv * 16 + row;

  constexpr size_t POOL =
      sizeof(L0LDS) > sizeof(L1LDS) ? sizeof(L0LDS) : sizeof(L1LDS);
  __shared__ __align__(16) char pool[POOL];

  if (blockIdx.x < NWGH) {
    // ================= L0 ROLE: chunk ch =================
    if (ch >= NCHUNK) return;
    L0LDS& S = *(L0LDS*)pool;
    const int w  = blockIdx.x;
    const int b0 = w * 4;

    f16x8 Bh[4][4];
#pragma unroll
    for (int i = 0; i < 4; ++i) {
      const int g = i * 128 + j;
#pragma unroll
      for (int kt = 0; kt < 4; ++kt)
        Bh[i][kt] = *(const f16x8*)&w0h[g * HDIM + kt * 32 + kq * 8];
    }

    // stage this chunk's x as fp16 (2 threads per (b,ts) row)
    {
      const int r = tid >> 1, half = tid & 1;
      const int b = r >> 6, ts = r & (TC - 1);
      const float* src =
          &x[((size_t)(b0 + b) * T_SEQ + ch * TC + ts) * IN_DIM + half * 8];
      const float4 v0 = *(const float4*)&src[0];
      const float4 v1 = *(const float4*)&src[4];
      ushort_t* dst = &S.xlds[b][ts][half * 8];
      dst[0] = f16_bits(v0.x); dst[1] = f16_bits(v0.y);
      dst[2] = f16_bits(v0.z); dst[3] = f16_bits(v0.w);
      dst[4] = f16_bits(v1.x); dst[5] = f16_bits(v1.y);
      dst[6] = f16_bits(v1.z); dst[7] = f16_bits(v1.w);
      *(float4*)&S.xlds[b][ts][16 + half * 8] = (float4){0.f, 0.f, 0.f, 0.f};
    }

    float bz[4];
#pragma unroll
    for (int i = 0; i < 4; ++i) bz[i] = bih0[i * 128 + j] + bhh0[i * 128 + j];
    float hc = h1s[(size_t)(b0 + kq) * HDIM + j];
    float cc = c1s[(size_t)(b0 + kq) * HDIM + j];
    S.hfA[kq][j] = f16_bits(hc);
    __syncthreads();

    ushort_t* hbp = h1buf + ((size_t)(ch & 1) * NWGH + w) * (TC * 4 * HDIM) +
                    (size_t)kq * HDIM + j;

#define L0_STEP(HIN, HOUT, TT)                                              \
  {                                                                         \
    const float4 zcu =                                                      \
        *(const float4*)&S.gx0s[((((TT) & 7) * 4 + kq) * 128 + j) * 4];     \
    f32x4 aH[4];                                                            \
    _Pragma("unroll") for (int i = 0; i < 4; ++i)                           \
        aH[i] = (f32x4){0.f, 0.f, 0.f, 0.f};                                \
    _Pragma("unroll") for (int kt = 0; kt < 4; ++kt) {                      \
      const f16x8 ah = *(const f16x8*)&HIN[bq][kt * 32 + kq * 8];           \
      _Pragma("unroll") for (int i = 0; i < 4; ++i)                         \
          aH[i] = MFMA16(ah, Bh[i][kt], aH[i]);                             \
    }                                                                       \
    const float ig = sigf(aH[0][0] + zcu.x);                                \
    const float fg = sigf(aH[1][0] + zcu.y);                                \
    const float gg = tanhf_fast(aH[2][0] + zcu.z);                          \
    const float og = sigf(aH[3][0] + zcu.w);                                \
    cc = fg * cc + ig * gg;                                                 \
    hc = og * tanhf_fast(cc);                                               \
    const ushort_t hbits = f16_bits(hc);                                    \
    HOUT[kq][j] = hbits;                                                    \
    *hbp = hbits;                                                           \
    hbp += 4 * HDIM;                                                        \
    bar_lds();                                                              \
  }

    for (int sc = 0; sc < TC / 8; ++sc) {
      // ---- sub-chunk x-GEMM: gx0 = x . Wih0^T + bias (hi+lo) -> LDS ----
      {
        f16x8 Bxh[4], Bxl[4];
#pragma unroll
        for (int i = 0; i < 4; ++i) {
          const int g = i * 128 + j;
          Bxh[i] = *(const f16x8*)&wxh[g * 32 + kq * 8];
          Bxl[i] = *(const f16x8*)&wxl[g * 32 + kq * 8];
        }
#pragma unroll
        for (int mt = 0; mt < 2; ++mt) {
          const f16x8 a = *(const f16x8*)
              &S.xlds[row & 3][sc * 8 + mt * 4 + (row >> 2)][kq * 8];
          f32x4 acc[4];
#pragma unroll
          for (int i = 0; i < 4; ++i) acc[i] = (f32x4){0.f, 0.f, 0.f, 0.f};
#pragma unroll
          for (int i = 0; i < 4; ++i) acc[i] = MFMA16(a, Bxh[i], acc[i]);
#pragma unroll
          for (int i = 0; i < 4; ++i) acc[i] = MFMA16(a, Bxl[i], acc[i]);
#pragma unroll
          for (int r = 0; r < 4; ++r) {
            float4 o;
            o.x = acc[0][r] + bz[0];
            o.y = acc[1][r] + bz[1];
            o.z = acc[2][r] + bz[2];
            o.w = acc[3][r] + bz[3];
            *(float4*)&S.gx0s[(((mt * 4 + kq) * 4 + r) * 128 + j) * 4] = o;
          }
        }
      }
      __syncthreads();
#pragma unroll 1
      for (int q = 0; q < 4; ++q) {
        const int tt = sc * 8 + q * 2;
        L0_STEP(S.hfA, S.hfB, tt);
        L0_STEP(S.hfB, S.hfA, tt + 1);
      }
    }
#undef L0_STEP

    h1s[(size_t)(b0 + kq) * HDIM + j] = hc;
    c1s[(size_t)(b0 + kq) * HDIM + j] = cc;
  } else {
    // ================= L1 ROLE: gemm + recurrence, FC at chunk end =========
    if (ch == 0) return;
    L1LDS& S = *(L1LDS*)pool;
    const int w  = blockIdx.x - NWGH;
    const int b0 = w * 4;

    const ushort_t* hb =
        h1buf + ((size_t)((ch - 1) & 1) * NWGH + w) * (TC * 4 * HDIM);
    float* gx = gx1buf + (size_t)w * (TC * 4 * HDIM * 4);

    if (tid < HDIM) S.wfl[tid] = Wfc[tid];

    // ---- gemm: gx1 = h1 . Wih1^T + biases (hi only), own 4 batches ----
    {
      f16x8 Gh[4][4];
      float bz1[4];
#pragma unroll
      for (int i = 0; i < 4; ++i) {
        const int g = i * 128 + j;
#pragma unroll
        for (int kt = 0; kt < 4; ++kt)
          Gh[i][kt] = *(const f16x8*)&wi1h[g * HDIM + kt * 32 + kq * 8];
        bz1[i] = bih1[i * 128 + j] + bhh1[i * 128 + j];
      }
#pragma unroll 2
      for (int mt = 0; mt < TC * 4 / 16; ++mt) {
        f32x4 acc[4];
#pragma unroll
        for (int i = 0; i < 4; ++i) acc[i] = (f32x4){0.f, 0.f, 0.f, 0.f};
#pragma unroll
        for (int kt = 0; kt < 4; ++kt) {
          const f16x8 a =
              *(const f16x8*)&hb[(size_t)(mt * 16 + row) * HDIM + kt * 32 + kq * 8];
#pragma unroll
          for (int i = 0; i < 4; ++i) acc[i] = MFMA16(a, Gh[i][kt], acc[i]);
        }
#pragma unroll
        for (int r = 0; r < 4; ++r) {
          const int m = mt * 16 + kq * 4 + r;
          float4 o;
          o.x = acc[0][r] + bz1[0];
          o.y = acc[1][r] + bz1[1];
          o.z = acc[2][r] + bz1[2];
          o.w = acc[3][r] + bz1[3];
          *(float4*)&gx[((size_t)m * HDIM + j) * 4] = o;
        }
      }
    }

    float hc = h2s[(size_t)(b0 + kq) * HDIM + j];
    float cc = c2s[(size_t)(b0 + kq) * HDIM + j];
    S.hfA[kq][j] = f16_bits(hc);
    __syncthreads();  // drains gemm stores (vmcnt) + hfA/wfl staging

    f16x8 Rh[4][4];
#pragma unroll
    for (int i = 0; i < 4; ++i) {
      const int g = i * 128 + j;
#pragma unroll
      for (int kt = 0; kt < 4; ++kt)
        Rh[i][kt] = *(const f16x8*)&w1h[g * HDIM + kt * 32 + kq * 8];
    }

    // per-step stride: 4 rows x HDIM x 4 floats = 2048 floats = 512 float4
    const float4* gxp = (const float4*)&gx[((size_t)kq * HDIM + j) * 4];
    float4 zcc = *gxp;
    gxp += 512;

#define L1_STEP(HIN, HOUT, TT)                                              \
  {                                                                         \
    const float4 zcu = zcc;                                                 \
    if ((TT) + 1 < TC) { zcc = *gxp; gxp += 512; }                          \
    f32x4 aH[4];                                                            \
    _Pragma("unroll") for (int i = 0; i < 4; ++i)                           \
        aH[i] = (f32x4){0.f, 0.f, 0.f, 0.f};                                \
    _Pragma("unroll") for (int kt = 0; kt < 4; ++kt) {                      \
      const f16x8 ah = *(const f16x8*)&HIN[bq][kt * 32 + kq * 8];           \
      _Pragma("unroll") for (int i = 0; i < 4; ++i)                         \
          aH[i] = MFMA16(ah, Rh[i][kt], aH[i]);                             \
    }                                                                       \
    const float ig = sigf(aH[0][0] + zcu.x);                                \
    const float fg = sigf(aH[1][0] + zcu.y);                                \
    const float gg = tanhf_fast(aH[2][0] + zcu.z);                          \
    const float og = sigf(aH[3][0] + zcu.w);                                \
    cc = fg * cc + ig * gg;                                                 \
    hc = og * tanhf_fast(cc);                                               \
    const ushort_t hbits = f16_bits(hc);                                    \
    HOUT[kq][j] = hbits;                                                    \
    S.h2l[TT][kq][j] = hbits;                                               \
    bar_lds();                                                              \
  }

    for (int tt = 0; tt < TC; tt += 2) {
      L1_STEP(S.hfA, S.hfB, tt);
      L1_STEP(S.hfB, S.hfA, tt + 1);
    }
#undef L1_STEP

    h2s[(size_t)(b0 + kq) * HDIM + j] = hc;
    c2s[(size_t)(b0 + kq) * HDIM + j] = cc;

    // ---- FC pass over the chunk (latency-tolerant, once per chunk) ----
    // last bar_lds made all h2l writes visible
    if (tid < TC * 4) {
      const int tt = tid >> 2, b = tid & 3;
      const float bfcv = bfc[0];
      float s0 = 0.f, s1 = 0.f, s2 = 0.f, s3 = 0.f;
#pragma unroll
      for (int q = 0; q < HDIM / 8; ++q) {
        const f16x8 hv = *(const f16x8*)&S.h2l[tt][b][q * 8];
        const float* wq = &S.wfl[q * 8];
        s0 += fmaxf((float)hv[0], 0.f) * wq[0];
        s1 += fmaxf((float)hv[1], 0.f) * wq[1];
        s2 += fmaxf((float)hv[2], 0.f) * wq[2];
        s3 += fmaxf((float)hv[3], 0.f) * wq[3];
        s0 += fmaxf((float)hv[4], 0.f) * wq[4];
        s1 += fmaxf((float)hv[5], 0.f) * wq[5];
        s2 += fmaxf((float)hv[6], 0.f) * wq[6];
        s3 += fmaxf((float)hv[7], 0.f) * wq[7];
      }
      const float s = s0 + s1 + s2 + s3 + bfcv;
      out[(size_t)(b0 + b) * T_SEQ + (ch - 1) * TC + tt] = fmaxf(s, 0.0f);
    }
  }
}

extern "C" void kernel_launch(void* const* d_in, const int* in_sizes, int n_in,
                              void* d_out, int out_size, void* d_ws, size_t ws_size,
                              hipStream_t stream)
{
  const float* x    = (const float*)d_in[0];
  const float* Wih0 = (const float*)d_in[1];
  const float* Whh0 = (const float*)d_in[2];
  const float* bih0 = (const float*)d_in[3];
  const float* bhh0 = (const float*)d_in[4];
  const float* Wih1 = (const float*)d_in[5];
  const float* Whh1 = (const float*)d_in[6];
  const float* bih1 = (const float*)d_in[7];
  const float* bhh1 = (const float*)d_in[8];
  const float* Wfc  = (const float*)d_in[9];
  const float* bfc  = (const float*)d_in[10];
  float* out = (float*)d_out;

  const size_t stateN = (size_t)NBATCH * HDIM;  // 65536
  float* h1s = (float*)d_ws;
  float* c1s = h1s + stateN;
  float* h2s = c1s + stateN;
  float* c2s = h2s + stateN;
  ushort_t* w0h  = (ushort_t*)(c2s + stateN);
  ushort_t* w0l  = w0h  + stateN;
  ushort_t* w1h  = w0l  + stateN;
  ushort_t* w1l  = w1h  + stateN;
  ushort_t* wi1h = w1l  + stateN;
  ushort_t* wi1l = wi1h + stateN;
  ushort_t* wxh  = wi1l + stateN;
  ushort_t* wxl  = wxh  + 512 * 32;
  ushort_t* h1buf = wxl + 512 * 32;                       // 2*NWGH*TC*4*HDIM fp16
  float* gx1buf = (float*)(h1buf + (size_t)2 * NWGH * TC * 4 * HDIM);

  // zero-init recurrent states (h0 = c0 = 0)
  (void)hipMemsetAsync(d_ws, 0, 4 * stateN * sizeof(float), stream);
  hipLaunchKernelGGL(prep_weights, dim3(256), dim3(256), 0, stream,
                     Whh0, Whh1, Wih0, Wih1,
                     w0h, w0l, w1h, w1l, wxh, wxl, wi1h, wi1l);

  for (int ch = 0; ch <= NCHUNK; ++ch) {
    hipLaunchKernelGGL(lstm_pipe, dim3(2 * NWGH), dim3(512), 0, stream,
                       x, w0h, wxh, wxl, bih0, bhh0,
                       wi1h, w1h, bih1, bhh1, Wfc, bfc,
                       out, h1s, c1s, h2s, c2s, h1buf, gx1buf, ch);
  }
}